// Round 6
// baseline (418.236 us; speedup 1.0000x reference)
//
#include <hip/hip_runtime.h>
#include <stdint.h>

// ---------------------------------------------------------------------------
// FeatureMapTransformer: dual cross-attention (rd / dr paths), B=2, C=512,
// H=W=64 -> N=M=4096.
//   Qt[n][c], Kt[m][c] (transposed conv outs), V[c][m]        (bf16)
//   Et[n][m] = bf16(exp(sum_c Kt[m][c] Qt[n][c]))             (k_qk)
//   partial S[m] = sum_n exp(T) fused into k_qk -> c[m] = 1/S (k_stats2)
//   V'[c][m] = V[c][m] * c[m]                                 (k_vscale)
//   O[c][n]  = sum_m V'[c][m] E[n][m]  (pure bf16 GEMM)       (k_pv)
//   out = relu(gamma*O + resid)  (fused k_pv epilogue)
// Round-15 theory: k_pv invariant at 105-116 us across three schedules
// (r3 coarse-128^2, r4 coarse-256col, r5 fine-phase) = the E-matrix L3
// stream. All had Tc=128 -> E read 4x = 536 MB from Infinity Cache at
// ~5 TB/s ~= 108 us. (Not LDS: 44 B/cyc = 34% of peak. Not HBM: 1.24
// TB/s. FETCH ~98 MB ~= E read once from HBM, re-reads are L3 hits.)
// Fix: Tc=256 halves the L3 stream (268 MB ~= 54 us). Costs half-fill
// (only 2x16x4 = 128 blocks of 256^2 exist) -> MFMA floor on 128 CUs =
// 55 us; balanced at ~60-75. Geometry = m201's verified 256^2 template:
// 8 waves, wave tile 128x64 (acc[8][4]), BK=64, 128 KB LDS, per-K-tile
// two phases {12 ds_read; lgkm(0); setprio 32-MFMA; barrier; stage-half},
// counted vmcnt(8), stage only after the barrier proving all waves read
// that region. XCD map x = c + 2z + 8n -> XCD = 2z+c: V'-half (2 MB)
// L2-resident per XCD; E streamed from L3 exactly twice.
// ---------------------------------------------------------------------------

typedef __attribute__((ext_vector_type(8))) __bf16 bf16x8;
typedef __attribute__((ext_vector_type(4))) float f32x4;

__device__ __forceinline__ unsigned short f2bf(float f) {
  union { float f; unsigned u; } v; v.f = f;
  unsigned r = v.u + 0x7FFFu + ((v.u >> 16) & 1u);
  return (unsigned short)(r >> 16);
}
__device__ __forceinline__ float bf2f(unsigned short b) {
  union { unsigned u; float f; } v; v.u = ((unsigned)b) << 16;
  return v.f;
}

__device__ __forceinline__ void async_copy16(const unsigned short* g,
                                             unsigned short* l) {
  __builtin_amdgcn_global_load_lds(
      (const __attribute__((address_space(1))) unsigned int*)g,
      (__attribute__((address_space(3))) unsigned int*)l, 16, 0, 0);
}

// Counted VMEM wait (literal immediates only). Memory clobber pins all
// memory ops (ds_read / global_load_lds) on the correct side.
template <int N>
__device__ __forceinline__ void waitcnt_vm() {
  if constexpr (N == 0) asm volatile("s_waitcnt vmcnt(0)" ::: "memory");
  else if constexpr (N == 4) asm volatile("s_waitcnt vmcnt(4)" ::: "memory");
  else if constexpr (N == 6) asm volatile("s_waitcnt vmcnt(6)" ::: "memory");
  else asm volatile("s_waitcnt vmcnt(8)" ::: "memory");
}

// C[128x128 at (rowbase,colbase)] += A[row][k] * B[col][k]^T, K-contig A/B.
// lds layout: [2 buffers][A|B][NSUB][128x32 sub-tile = 4096 shorts].
// 16B chunk c of row r lives at slot c^((r>>1)&3) (pre-swizzled on the
// global source side; global_load_lds dest stays linear).
template <int NSUB>
__device__ __forceinline__ void gemm_core(
    const unsigned short* __restrict__ Ag, const unsigned short* __restrict__ Bg,
    int K, int lda, int ldb, int rowbase, int colbase,
    f32x4 (&acc)[4][4], unsigned short* lds) {
  const int tid = threadIdx.x;
  const int w = tid >> 6, lane = tid & 63;
  const int quad = lane >> 4, l16 = lane & 15;
  const int wm = (w >> 1) << 6, wn = (w & 1) << 6;
  const int rbase = (w << 5) + (lane >> 2);
  const int BK = 32 * NSUB;

  auto stage = [&](int k0, unsigned short* buf) {
#pragma unroll
    for (int half = 0; half < NSUB; ++half) {
      int kh = k0 + (half << 5);
      unsigned short* Ah = buf + (half << 12);
      unsigned short* Bh = buf + (NSUB << 12) + (half << 12);
#pragma unroll
      for (int i = 0; i < 2; ++i) {
        int rloc = rbase + (i << 4);
        int cg = (lane & 3) ^ ((rloc >> 1) & 3);
        int koff = kh + (cg << 3);
        int ldsoff = ((w << 5) + (i << 4)) << 5;
        async_copy16(Ag + (size_t)(rowbase + rloc) * lda + koff, Ah + ldsoff);
        async_copy16(Bg + (size_t)(colbase + rloc) * ldb + koff, Bh + ldsoff);
      }
    }
  };

  auto compute = [&](const unsigned short* buf) {
#pragma unroll
    for (int half = 0; half < NSUB; ++half) {
      const unsigned short* Ah = buf + (half << 12);
      const unsigned short* Bh = buf + (NSUB << 12) + (half << 12);
      bf16x8 af[4], bfr[4];
#pragma unroll
      for (int i = 0; i < 4; ++i) {
        int r = wm + (i << 4) + l16;
        af[i] = *(const bf16x8*)(Ah + (r << 5) + ((quad ^ ((r >> 1) & 3)) << 3));
      }
#pragma unroll
      for (int j = 0; j < 4; ++j) {
        int r = wn + (j << 4) + l16;
        bfr[j] = *(const bf16x8*)(Bh + (r << 5) + ((quad ^ ((r >> 1) & 3)) << 3));
      }
#pragma unroll
      for (int i = 0; i < 4; ++i)
#pragma unroll
        for (int j = 0; j < 4; ++j)
          acc[i][j] = __builtin_amdgcn_mfma_f32_16x16x32_bf16(af[i], bfr[j], acc[i][j], 0, 0, 0);
    }
  };

  unsigned short* b0 = lds;                   // current compute buffer
  unsigned short* b1 = lds + (NSUB << 13);    // in-flight prefetch buffer
  const int nt = K / BK;

  stage(0, b0);
  stage(BK, b1);
  for (int t = 0; t < nt - 1; ++t) {
    waitcnt_vm<4 * NSUB>();          // own stage(t) retired; stage(t+1) rides
    __builtin_amdgcn_s_barrier();    // => all waves' stage(t) complete
    compute(b0);
    __builtin_amdgcn_sched_barrier(0);
    __builtin_amdgcn_s_barrier();    // all waves done reading b0
    if (t + 2 < nt) stage((t + 2) * BK, b0);
    unsigned short* tmp = b0; b0 = b1; b1 = tmp;
  }
  waitcnt_vm<0>();                   // final tile: drain
  __builtin_amdgcn_s_barrier();
  compute(b0);
  __syncthreads();                   // LDS safe for caller epilogue reuse
}

// ---------------- weight fp32 -> bf16 (vectorized) -----------------------
struct WArgs { const float* src[6]; unsigned short* dst[6]; };
__global__ __launch_bounds__(256) void k_cvtw(WArgs a) {
  int z = blockIdx.y;
  int i = (blockIdx.x * 256 + threadIdx.x) << 3;
  const float* s = a.src[z] + i;
  float4 v0 = *(const float4*)s;
  float4 v1 = *(const float4*)(s + 4);
  unsigned short pk[8] = {f2bf(v0.x), f2bf(v0.y), f2bf(v0.z), f2bf(v0.w),
                          f2bf(v1.x), f2bf(v1.y), f2bf(v1.z), f2bf(v1.w)};
  *(int4*)(a.dst[z] + i) = *(int4*)pk;
}

// ---------------- transpose+convert: x[b][c][n] f32 -> Xt[b][n][c] bf16 --
// 64n x 32c tile: float4 coalesced reads -> f32 LDS (stride 68: 16B-aligned
// float4 stores) -> 8 scalar LDS reads (4-way bank = 1.58x, acceptable) ->
// packed int4 bf16x8 stores (wave writes 1 KB in optimal 32B sectors).
struct TArgs { const float* src[4]; unsigned short* dst[4]; };
__global__ __launch_bounds__(256) void k_tcvt(TArgs a) {
  __shared__ float tile[32][68];
  int z = blockIdx.z;  // array*2 + b
  const float* src = a.src[z >> 1] + (size_t)(z & 1) * (512 * 4096);
  unsigned short* dst = a.dst[z >> 1] + (size_t)(z & 1) * (4096 * 512);
  int n0 = blockIdx.x << 6;  // 64 n
  int c0 = blockIdx.y << 5;  // 32 c
  int tid = threadIdx.x;
  int q = tid & 15, r0 = tid >> 4;  // 16 lanes/row, 16 c-rows/pass
#pragma unroll
  for (int pass = 0; pass < 2; ++pass) {
    int r = r0 + (pass << 4);
    *(float4*)&tile[r][q << 2] =
        *(const float4*)(src + (size_t)(c0 + r) * 4096 + n0 + (q << 2));
  }
  __syncthreads();
  int j = tid >> 2, c8 = (tid & 3) << 3;  // n row j, 8 c's per thread
  unsigned short pk[8];
#pragma unroll
  for (int k = 0; k < 8; ++k) pk[k] = f2bf(tile[c8 + k][j]);
  *(int4*)(dst + (size_t)(n0 + j) * 512 + c0 + c8) = *(int4*)pk;
}

// ---------------- conv1x1 GEMMs: Y = W X^T + bias ------------------------
// trans=1 (Q,K): operand-swapped -> rows=n (A=X), cols=o (B=W); store
// out[n][o] with o in the lane dim. trans=0 (V): rows=o, cols=n.
struct ConvArgs {
  const unsigned short* W[12];
  const unsigned short* X[12];
  const float* bias[12];
  unsigned short* out[12];
  int trans[12];
};
__global__ __launch_bounds__(256) void k_conv(ConvArgs a) {
  __shared__ unsigned short sh[16384];  // 2 buf x (A 4K + B 4K shorts) = 32 KB
  int z = blockIdx.z;
  int trans = a.trans[z];
  int rowbase = (trans ? blockIdx.x : blockIdx.y) << 7;
  int colbase = (trans ? blockIdx.y : blockIdx.x) << 7;
  const unsigned short* Ag = trans ? a.X[z] : a.W[z];
  const unsigned short* Bg = trans ? a.W[z] : a.X[z];
  f32x4 acc[4][4];
#pragma unroll
  for (int i = 0; i < 4; ++i)
#pragma unroll
    for (int j = 0; j < 4; ++j) acc[i][j] = (f32x4){0.f, 0.f, 0.f, 0.f};
  gemm_core<1>(Ag, Bg, 512, 512, 512, rowbase, colbase, acc, sh);

  const int tid = threadIdx.x, w = tid >> 6, lane = tid & 63;
  const int quad = lane >> 4, l16 = lane & 15;
  const int wm = (w >> 1) << 6, wn = (w & 1) << 6;
  const float* bias = a.bias[z];
  unsigned short* out = a.out[z];
  if (trans) {
    float bo[4];
#pragma unroll
    for (int j = 0; j < 4; ++j) bo[j] = bias[colbase + wn + (j << 4) + l16];
#pragma unroll
    for (int i = 0; i < 4; ++i) {
      int n0 = rowbase + wm + (i << 4) + (quad << 2);
#pragma unroll
      for (int j = 0; j < 4; ++j) {
        int o = colbase + wn + (j << 4) + l16;
        out[(size_t)(n0 + 0) * 512 + o] = f2bf(acc[i][j].x + bo[j]);
        out[(size_t)(n0 + 1) * 512 + o] = f2bf(acc[i][j].y + bo[j]);
        out[(size_t)(n0 + 2) * 512 + o] = f2bf(acc[i][j].z + bo[j]);
        out[(size_t)(n0 + 3) * 512 + o] = f2bf(acc[i][j].w + bo[j]);
      }
    }
  } else {
#pragma unroll
    for (int i = 0; i < 4; ++i) {
      int o0 = rowbase + wm + (i << 4) + (quad << 2);
      float b0 = bias[o0], b1 = bias[o0 + 1], b2 = bias[o0 + 2], b3 = bias[o0 + 3];
#pragma unroll
      for (int j = 0; j < 4; ++j) {
        int n = colbase + wn + (j << 4) + l16;
        out[(size_t)(o0 + 0) * 4096 + n] = f2bf(acc[i][j].x + b0);
        out[(size_t)(o0 + 1) * 4096 + n] = f2bf(acc[i][j].y + b1);
        out[(size_t)(o0 + 2) * 4096 + n] = f2bf(acc[i][j].z + b2);
        out[(size_t)(o0 + 3) * 4096 + n] = f2bf(acc[i][j].w + b3);
      }
    }
  }
}

// ---------------- Et[n][m] = exp(Qt Kt^T), fused partial sum S[m] --------
// OPERAND-SWAPPED: A=Qt (rows=n), B=Kt (cols=m) -> m is the lane dim.
// 256x256 tile, 8 waves (wave grid 2r x 4c, wave tile 128x64), BK=32.
// LDS: 2 buf x (A 256x32 + B 256x32) = 64 KB. Counted-vmcnt pipeline.
// XCD z-clustering: z=(rx>>1)&3 -> XCD pair {2z,2z+1} works one z.
struct QKArgs {
  const unsigned short* Q[4]; const unsigned short* K[4]; unsigned short* T[4];
  float* pz;  // [4 z][16 nblk][4096 m] partial sums
};
__global__ __launch_bounds__(512) void k_qk(QKArgs a) {
  __shared__ unsigned short sh[32768];  // 64 KB
  int rx = blockIdx.x, ry = blockIdx.y, rz = blockIdx.z;
  int z = (rx >> 1) & 3;                                    // XCD = rx&7
  int mb = (rx & 1) | (((rx >> 3) & 1) << 1) | (rz << 2);   // bijective remap
  int nbase = ry << 8;  // 256 rows = n
  int mbase = mb << 8;  // 256 cols = m
  const unsigned short* Ag = a.Q[z];
  const unsigned short* Bg = a.K[z];

  const int tid = threadIdx.x;
  const int w = tid >> 6, lane = tid & 63;
  const int quad = lane >> 4, l16 = lane & 15;
  const int wr = w >> 2, wc = w & 3;
  const int wm = wr << 7;       // wave A-row base (0/128)
  const int wn = wc << 6;       // wave B-row base (0/64/128/192)
  const int rbase = (w << 5) + (lane >> 2);

  f32x4 acc[8][4];
#pragma unroll
  for (int i = 0; i < 8; ++i)
#pragma unroll
    for (int j = 0; j < 4; ++j) acc[i][j] = (f32x4){0.f, 0.f, 0.f, 0.f};

  auto stage = [&](int k0, unsigned short* buf) {
    unsigned short* Ah = buf;
    unsigned short* Bh = buf + 8192;
#pragma unroll
    for (int i = 0; i < 2; ++i) {
      int rloc = rbase + (i << 4);
      int cg = (lane & 3) ^ ((rloc >> 1) & 3);
      int koff = k0 + (cg << 3);
      int ldsoff = ((w << 5) + (i << 4)) << 5;
      async_copy16(Ag + (size_t)(nbase + rloc) * 512 + koff, Ah + ldsoff);
      async_copy16(Bg + (size_t)(mbase + rloc) * 512 + koff, Bh + ldsoff);
    }
  };

  auto compute = [&](const unsigned short* buf) {
    const unsigned short* Ah = buf;
    const unsigned short* Bh = buf + 8192;
    bf16x8 af[8], bfr[4];
#pragma unroll
    for (int i = 0; i < 8; ++i) {
      int r = wm + (i << 4) + l16;
      af[i] = *(const bf16x8*)(Ah + (r << 5) + ((quad ^ ((r >> 1) & 3)) << 3));
    }
#pragma unroll
    for (int j = 0; j < 4; ++j) {
      int r = wn + (j << 4) + l16;
      bfr[j] = *(const bf16x8*)(Bh + (r << 5) + ((quad ^ ((r >> 1) & 3)) << 3));
    }
#pragma unroll
    for (int i = 0; i < 8; ++i)
#pragma unroll
      for (int j = 0; j < 4; ++j)
        acc[i][j] = __builtin_amdgcn_mfma_f32_16x16x32_bf16(af[i], bfr[j], acc[i][j], 0, 0, 0);
  };

  unsigned short* b0 = sh;
  unsigned short* b1 = sh + 16384;
  stage(0, b0);
  stage(32, b1);
  for (int t = 0; t < 15; ++t) {
    waitcnt_vm<4>();
    __builtin_amdgcn_s_barrier();
    compute(b0);
    __builtin_amdgcn_sched_barrier(0);
    __builtin_amdgcn_s_barrier();
    if (t + 2 < 16) stage((t + 2) << 5, b0);
    unsigned short* tmp = b0; b0 = b1; b1 = tmp;
  }
  waitcnt_vm<0>();
  __builtin_amdgcn_s_barrier();
  compute(b0);
  __syncthreads();

  unsigned short* T = a.T[z];
  float sjv[4] = {0.f, 0.f, 0.f, 0.f};
#pragma unroll
  for (int i = 0; i < 8; ++i) {
    int n0 = nbase + wm + (i << 4) + (quad << 2);
#pragma unroll
    for (int j = 0; j < 4; ++j) {
      int m = mbase + wn + (j << 4) + l16;
      float e0 = __expf(acc[i][j].x);
      float e1 = __expf(acc[i][j].y);
      float e2 = __expf(acc[i][j].z);
      float e3 = __expf(acc[i][j].w);
      T[(size_t)(n0 + 0) * 4096 + m] = f2bf(e0);
      T[(size_t)(n0 + 1) * 4096 + m] = f2bf(e1);
      T[(size_t)(n0 + 2) * 4096 + m] = f2bf(e2);
      T[(size_t)(n0 + 3) * 4096 + m] = f2bf(e3);
      sjv[j] += e0 + e1 + e2 + e3;
    }
  }
  float* red = (float*)sh;  // [8 waves][64 m-local]
#pragma unroll
  for (int j = 0; j < 4; ++j) {
    float s = sjv[j];
    s += __shfl_xor(s, 16, 64);
    s += __shfl_xor(s, 32, 64);
    if (quad == 0) red[(w << 6) + (j << 4) + l16] = s;
  }
  __syncthreads();
  if (tid < 256) {
    // wave (wr=0) slot == tid, wave (wr=1) slot == tid + 256
    float S = red[tid] + red[tid + 256];
    a.pz[((z << 4) + ry) * 4096 + mbase + tid] = S;
  }
}

// ---------------- merge 16 partials -> c[m] = 1/S ------------------------
__global__ __launch_bounds__(256) void k_stats2(const float* __restrict__ pz,
                                                float* __restrict__ c) {
  int m = (blockIdx.x << 8) + threadIdx.x;
  int z = blockIdx.y;
  float S = 0.f;
#pragma unroll
  for (int k = 0; k < 16; ++k) S += pz[((z << 4) + k) * 4096 + m];
  c[z * 4096 + m] = 1.f / S;
}

// ---------------- V'[c][m] = V[c][m] * c[m] (in place) -------------------
struct VSArgs { unsigned short* V[4]; const float* c; };
__global__ __launch_bounds__(256) void k_vscale(VSArgs a) {
  int z = blockIdx.y;
  int t = blockIdx.x * 256 + threadIdx.x;
  int m0 = (t & 511) << 3;
  int row = t >> 9;
  unsigned short* p = a.V[z] + (size_t)row * 4096 + m0;
  const float* cz = a.c + z * 4096 + m0;
  int4 raw = *(const int4*)p;
  unsigned short* u = (unsigned short*)&raw;
#pragma unroll
  for (int j = 0; j < 8; ++j) u[j] = f2bf(bf2f(u[j]) * cz[j]);
  *(int4*)p = raw;
}

// ---------------- O = V' E, epilogue relu(gamma*O + resid) ---------------
// 256x256 tile (Tc=256 halves the E L3 stream), 8 waves, wave tile 128c x
// 64n, acc[8][4], BK=64 in 2 subs of 32k. LDS 128 KB = 2 buf x (A 256x64
// + B 256x64). Grid 128 blocks (half fill -- only 128 such tiles exist;
// floors: E-L3 268 MB ~54 us, MFMA on 128 CUs ~55 us). Per K-tile: two
// phases {12 ds_read; lgkm(0); setprio 32 MFMA; barrier; stage-half(t+2)};
// counted vmcnt(8); stage placed only after the barrier proving all waves
// consumed that LDS region. XCD = x&7 = 2z+c: V'-half L2-resident.
struct PVArgs {
  const unsigned short* V[4];
  const unsigned short* P[4];  // Et[n][m]
  const float* resid[4];
  const float* gamma[4];
  float* out[4];
};
__global__ __launch_bounds__(512) void k_pv(PVArgs a) {
  __shared__ unsigned short sh[65536];  // 128 KB
  int x = blockIdx.x;          // x = c + 2z + 8n  ->  XCD = x&7 = 2z+c
  int cb = x & 1;
  int z  = (x >> 1) & 3;
  int nb = x >> 3;             // 0..15
  int cbase = cb << 8;         // 256 c rows
  int nbase = nb << 8;         // 256 n rows
  const unsigned short* Ag = a.V[z];   // V'[c][m], stride 4096
  const unsigned short* Bg = a.P[z];   // E[n][m],  stride 4096

  const int tid = threadIdx.x;
  const int w = tid >> 6, lane = tid & 63;
  const int quad = lane >> 4, l16 = lane & 15;
  const int wr = w >> 2, wc = w & 3;   // wave grid 2c x 4n
  const int wm = wr << 7;              // c offset 0/128 (wave covers 128 c)
  const int wn = wc << 6;              // n offset 0..192

  f32x4 acc[8][4];
#pragma unroll
  for (int i = 0; i < 8; ++i)
#pragma unroll
    for (int j = 0; j < 4; ++j) acc[i][j] = (f32x4){0.f, 0.f, 0.f, 0.f};

  // Buffer layout (shorts), stride 32768 (64 KB):
  //   A: [s][256 r][32 k] at s*8192 + r*32 + slot*8
  //   B: same at +16384. Chunk slot = chunk ^ ((r>>1)&3), pre-swizzled src.
  const int srow = tid >> 2;                       // 0..127
  const int scg  = (tid & 3) ^ ((srow >> 1) & 3);
  auto stageHalf = [&](int k0, int s, unsigned short* buf) {
    int koff = k0 + (s << 5) + (scg << 3);
    unsigned short* As = buf + (s << 13);
    unsigned short* Bs = buf + 16384 + (s << 13);
    async_copy16(Ag + (size_t)(cbase + srow) * 4096 + koff, As + (w << 9));
    async_copy16(Ag + (size_t)(cbase + 128 + srow) * 4096 + koff,
                 As + 4096 + (w << 9));
    async_copy16(Bg + (size_t)(nbase + srow) * 4096 + koff, Bs + (w << 9));
    async_copy16(Bg + (size_t)(nbase + 128 + srow) * 4096 + koff,
                 Bs + 4096 + (w << 9));
  };

  bf16x8 af[8], bfr[4];
  auto rdfrag = [&](const unsigned short* buf, int s) {
    const unsigned short* As = buf + (s << 13);
    const unsigned short* Bs = buf + 16384 + (s << 13);
#pragma unroll
    for (int i = 0; i < 8; ++i) {
      int r = wm + (i << 4) + l16;
      af[i] = *(const bf16x8*)(As + (r << 5) + ((quad ^ ((r >> 1) & 3)) << 3));
    }
#pragma unroll
    for (int j = 0; j < 4; ++j) {
      int r = wn + (j << 4) + l16;
      bfr[j] = *(const bf16x8*)(Bs + (r << 5) + ((quad ^ ((r >> 1) & 3)) << 3));
    }
  };

  auto mfma32 = [&]() {
#pragma unroll
    for (int i = 0; i < 8; ++i)
#pragma unroll
      for (int j = 0; j < 4; ++j)
        acc[i][j] = __builtin_amdgcn_mfma_f32_16x16x32_bf16(af[i], bfr[j], acc[i][j], 0, 0, 0);
  };

  unsigned short* b0 = sh;
  unsigned short* b1 = sh + 32768;

  stageHalf(0, 0, b0);  stageHalf(0, 1, b0);    // tile 0 (8 loads)
  stageHalf(64, 0, b1); stageHalf(64, 1, b1);   // tile 1 (8 loads)

  for (int t = 0; t < 64; ++t) {
    unsigned short* cur = (t & 1) ? b1 : b0;
    // tile-t readiness: all but newest 8 outstanding retired (in-order cnt)
    if (t < 63) waitcnt_vm<8>(); else waitcnt_vm<0>();
    __builtin_amdgcn_s_barrier();
    __builtin_amdgcn_sched_barrier(0);
    // phase 0: sub0
    rdfrag(cur, 0);
    asm volatile("s_waitcnt lgkmcnt(0)" ::: "memory");
    __builtin_amdgcn_s_setprio(1);
    mfma32();
    __builtin_amdgcn_s_setprio(0);
    __builtin_amdgcn_sched_barrier(0);
    __builtin_amdgcn_s_barrier();     // all waves consumed cur.s0
    __builtin_amdgcn_sched_barrier(0);
    if (t + 2 < 64) stageHalf((t + 2) << 6, 0, cur);
    // phase 1: sub1
    rdfrag(cur, 1);
    asm volatile("s_waitcnt lgkmcnt(0)" ::: "memory");
    __builtin_amdgcn_s_setprio(1);
    mfma32();
    __builtin_amdgcn_s_setprio(0);
    __builtin_amdgcn_sched_barrier(0);
    __builtin_amdgcn_s_barrier();     // all waves consumed cur.s1
    __builtin_amdgcn_sched_barrier(0);
    if (t + 2 < 64) stageHalf((t + 2) << 6, 1, cur);
  }

  float g = a.gamma[z][0];
  const float* R = a.resid[z];
  float* O = a.out[z];
#pragma unroll
  for (int i = 0; i < 8; ++i) {
    int c0 = cbase + wm + (i << 4) + (quad << 2);
#pragma unroll
    for (int j = 0; j < 4; ++j) {
      int n = nbase + wn + (j << 4) + l16;
      O[(size_t)(c0 + 0) * 4096 + n] = fmaxf(g * acc[i][j].x + R[(size_t)(c0 + 0) * 4096 + n], 0.f);
      O[(size_t)(c0 + 1) * 4096 + n] = fmaxf(g * acc[i][j].y + R[(size_t)(c0 + 1) * 4096 + n], 0.f);
      O[(size_t)(c0 + 2) * 4096 + n] = fmaxf(g * acc[i][j].z + R[(size_t)(c0 + 2) * 4096 + n], 0.f);
      O[(size_t)(c0 + 3) * 4096 + n] = fmaxf(g * acc[i][j].w + R[(size_t)(c0 + 3) * 4096 + n], 0.f);
    }
  }
}

// ---------------------------------------------------------------------------
extern "C" void kernel_launch(void* const* d_in, const int* in_sizes, int n_in,
                              void* d_out, int out_size, void* d_ws, size_t ws_size,
                              hipStream_t stream) {
  char* ws = (char*)d_ws;
  unsigned short* wb  = (unsigned short*)(ws);              //  6 x 512x512 bf16
  unsigned short* xt  = (unsigned short*)(ws + 3145728);    //  4 x [2][4096][512]
  unsigned short* qkv = (unsigned short*)(ws + 36700160);   // 12 x [4096x512]
  unsigned short* tt  = (unsigned short*)(ws + 87031808);   //  4 x [4096x4096]
  float* pz  = (float*)(ws + 3145728);                      // overlaps dead xt
  float* cb  = (float*)(ws + 3145728 + 2097152);

  // 1. weights -> bf16
  WArgs wa;
  for (int i = 0; i < 6; ++i) {
    wa.src[i] = (const float*)d_in[4 + 2 * i];
    wa.dst[i] = wb + (size_t)i * 262144;
  }
  k_cvtw<<<dim3(128, 6), 256, 0, stream>>>(wa);

  // 2. feature maps -> transposed bf16 Xt[b][n][c]
  TArgs ta;
  for (int ai = 0; ai < 4; ++ai) {
    ta.src[ai] = (const float*)d_in[ai];
    ta.dst[ai] = xt + (size_t)ai * 4194304;
  }
  k_tcvt<<<dim3(64, 16, 8), 256, 0, stream>>>(ta);

  // 3. six convs x two batches (q_rd, k_rd, v_rd, q_dr, k_dr, v_dr)
  const int srcArr[6] = {2, 0, 3, 3, 1, 1};
  const int trans[6] = {1, 1, 0, 1, 1, 0};
  ConvArgs ca;
  for (int ci = 0; ci < 6; ++ci)
    for (int b = 0; b < 2; ++b) {
      int zz = ci * 2 + b;
      ca.W[zz] = wb + (size_t)ci * 262144;
      ca.X[zz] = xt + (size_t)srcArr[ci] * 4194304 + (size_t)b * 2097152;
      ca.bias[zz] = (const float*)d_in[5 + 2 * ci];
      ca.out[zz] = qkv + (size_t)zz * 2097152;
      ca.trans[zz] = trans[ci];
    }
  k_conv<<<dim3(32, 4, 12), 256, 0, stream>>>(ca);

  // 4. Et[n][m] = exp(Qt Kt^T) + fused partial sums (256^2 tile, 8 waves)
  QKArgs qa;
  for (int path = 0; path < 2; ++path)
    for (int b = 0; b < 2; ++b) {
      int zz = path * 2 + b;
      qa.Q[zz] = qkv + (size_t)((path * 3 + 0) * 2 + b) * 2097152;  // Qt (rows=n)
      qa.K[zz] = qkv + (size_t)((path * 3 + 1) * 2 + b) * 2097152;  // Kt (cols=m)
      qa.T[zz] = tt + (size_t)zz * 16777216;
    }
  qa.pz = pz;
  k_qk<<<dim3(16, 16, 4), 512, 0, stream>>>(qa);

  // 5. merge partials -> c[m] = 1/S
  k_stats2<<<dim3(16, 4), 256, 0, stream>>>(pz, cb);

  // 6. V' = V * c[m]
  VSArgs va;
  for (int path = 0; path < 2; ++path)
    for (int b = 0; b < 2; ++b)
      va.V[path * 2 + b] = qkv + (size_t)((path * 3 + 2) * 2 + b) * 2097152;
  va.c = cb;
  k_vscale<<<dim3(1024, 4), 256, 0, stream>>>(va);

  // 7. O = V' E + fused epilogue (256^2 tile, BK=64, fine-phase, half-fill)
  PVArgs pa;
  const float* resid_src[2] = {(const float*)d_in[2], (const float*)d_in[3]};
  const float* gsrc[2] = {(const float*)d_in[16], (const float*)d_in[17]};
  for (int path = 0; path < 2; ++path)
    for (int b = 0; b < 2; ++b) {
      int zz = path * 2 + b;
      pa.V[zz] = qkv + (size_t)((path * 3 + 2) * 2 + b) * 2097152;
      pa.P[zz] = tt + (size_t)zz * 16777216;
      pa.resid[zz] = resid_src[path] + (size_t)b * 2097152;
      pa.gamma[zz] = gsrc[path];
      pa.out[zz] = (float*)d_out + (size_t)zz * 2097152;
    }
  k_pv<<<dim3(128), 512, 0, stream>>>(pa);
}

// Round 7
// 385.561 us; speedup vs baseline: 1.0847x; 1.0847x over previous
//
#include <hip/hip_runtime.h>
#include <stdint.h>

// ---------------------------------------------------------------------------
// FeatureMapTransformer: dual cross-attention (rd / dr paths), B=2, C=512,
// H=W=64 -> N=M=4096.
//   Qt[n][c], Kt[m][c] (transposed conv outs), V[c][m]        (bf16)
//   Et[n][m] = bf16(exp(sum_c Kt[m][c] Qt[n][c]))             (k_qk)
//   partial S[m] = sum_n exp(T) fused into k_qk -> c[m] = 1/S (k_stats2)
//   V'[c][m] = V[c][m] * c[m]                                 (k_vscale)
//   O[c][n]  = sum_m V'[c][m] E[n][m]  (pure bf16 GEMM)       (k_pv)
//   out = relu(gamma*O + resid)  (fused k_pv epilogue)
// E-L3-STREAM MODEL (r12-r16): k_pv is bound by the E-matrix Infinity-
// Cache stream at ~4.9 TB/s. Evidence: r3 (128^2 coarse) and r5 (Tn=256
// fine-phase) both stream E 4x = 536 MB and both measure 108.6/108.9 us.
// r6 (Tc=256, half-fill 128 blocks) halved the stream but collapsed
// request parallelism + MFMA capacity -> 150 us, FETCH 98->155 MB (L3
// temporal coalescing lost at low concurrency). Lesson: cut the stream
// WITHOUT leaving full fill.
// Round-17: Tc=256 x Tn=128 -> grid 2c x 32n x 4z = 256 blocks = exact
// fill. E read 2x/z = 268 MB L3 (~55 us); V' read 32x -> must be L2-
// resident: 1-D grid x = cb + 2z + 8nb pins XCD = 2z+cb, so one XCD's 32
// blocks share one (z,c-half) 2 MB V' slice (L2-hot, ~1.4 TB/s/XCD).
// cb-siblings (same E slice) are adjacent x -> concurrent -> L3 sharing.
// LDS 96 KB (A 256x64 + B 128x64, dbuf), wave tile 64x64, acc[4][4],
// r5's proven fine-phase schedule verbatim (counted vmcnt(6), fragment
// regs one phase ahead, setprio MFMA clusters, lgkm(0) only before the
// buffer-overwrite barrier). k_qk: reverted to r3's plain mapping (the
// XCD remap cost ~10 us total with no k_pv benefit; r3=371.2 best).
// ---------------------------------------------------------------------------

typedef __attribute__((ext_vector_type(8))) __bf16 bf16x8;
typedef __attribute__((ext_vector_type(4))) float f32x4;

__device__ __forceinline__ unsigned short f2bf(float f) {
  union { float f; unsigned u; } v; v.f = f;
  unsigned r = v.u + 0x7FFFu + ((v.u >> 16) & 1u);
  return (unsigned short)(r >> 16);
}
__device__ __forceinline__ float bf2f(unsigned short b) {
  union { unsigned u; float f; } v; v.u = ((unsigned)b) << 16;
  return v.f;
}

__device__ __forceinline__ void async_copy16(const unsigned short* g,
                                             unsigned short* l) {
  __builtin_amdgcn_global_load_lds(
      (const __attribute__((address_space(1))) unsigned int*)g,
      (__attribute__((address_space(3))) unsigned int*)l, 16, 0, 0);
}

// Counted VMEM wait (literal immediates only). Memory clobber pins all
// memory ops (ds_read / global_load_lds) on the correct side.
template <int N>
__device__ __forceinline__ void waitcnt_vm() {
  if constexpr (N == 0) asm volatile("s_waitcnt vmcnt(0)" ::: "memory");
  else if constexpr (N == 4) asm volatile("s_waitcnt vmcnt(4)" ::: "memory");
  else if constexpr (N == 6) asm volatile("s_waitcnt vmcnt(6)" ::: "memory");
  else asm volatile("s_waitcnt vmcnt(8)" ::: "memory");
}

// C[128x128 at (rowbase,colbase)] += A[row][k] * B[col][k]^T, K-contig A/B.
// lds layout: [2 buffers][A|B][NSUB][128x32 sub-tile = 4096 shorts].
// 16B chunk c of row r lives at slot c^((r>>1)&3) (pre-swizzled on the
// global source side; global_load_lds dest stays linear).
template <int NSUB>
__device__ __forceinline__ void gemm_core(
    const unsigned short* __restrict__ Ag, const unsigned short* __restrict__ Bg,
    int K, int lda, int ldb, int rowbase, int colbase,
    f32x4 (&acc)[4][4], unsigned short* lds) {
  const int tid = threadIdx.x;
  const int w = tid >> 6, lane = tid & 63;
  const int quad = lane >> 4, l16 = lane & 15;
  const int wm = (w >> 1) << 6, wn = (w & 1) << 6;
  const int rbase = (w << 5) + (lane >> 2);
  const int BK = 32 * NSUB;

  auto stage = [&](int k0, unsigned short* buf) {
#pragma unroll
    for (int half = 0; half < NSUB; ++half) {
      int kh = k0 + (half << 5);
      unsigned short* Ah = buf + (half << 12);
      unsigned short* Bh = buf + (NSUB << 12) + (half << 12);
#pragma unroll
      for (int i = 0; i < 2; ++i) {
        int rloc = rbase + (i << 4);
        int cg = (lane & 3) ^ ((rloc >> 1) & 3);
        int koff = kh + (cg << 3);
        int ldsoff = ((w << 5) + (i << 4)) << 5;
        async_copy16(Ag + (size_t)(rowbase + rloc) * lda + koff, Ah + ldsoff);
        async_copy16(Bg + (size_t)(colbase + rloc) * ldb + koff, Bh + ldsoff);
      }
    }
  };

  auto compute = [&](const unsigned short* buf) {
#pragma unroll
    for (int half = 0; half < NSUB; ++half) {
      const unsigned short* Ah = buf + (half << 12);
      const unsigned short* Bh = buf + (NSUB << 12) + (half << 12);
      bf16x8 af[4], bfr[4];
#pragma unroll
      for (int i = 0; i < 4; ++i) {
        int r = wm + (i << 4) + l16;
        af[i] = *(const bf16x8*)(Ah + (r << 5) + ((quad ^ ((r >> 1) & 3)) << 3));
      }
#pragma unroll
      for (int j = 0; j < 4; ++j) {
        int r = wn + (j << 4) + l16;
        bfr[j] = *(const bf16x8*)(Bh + (r << 5) + ((quad ^ ((r >> 1) & 3)) << 3));
      }
#pragma unroll
      for (int i = 0; i < 4; ++i)
#pragma unroll
        for (int j = 0; j < 4; ++j)
          acc[i][j] = __builtin_amdgcn_mfma_f32_16x16x32_bf16(af[i], bfr[j], acc[i][j], 0, 0, 0);
    }
  };

  unsigned short* b0 = lds;                   // current compute buffer
  unsigned short* b1 = lds + (NSUB << 13);    // in-flight prefetch buffer
  const int nt = K / BK;

  stage(0, b0);
  stage(BK, b1);
  for (int t = 0; t < nt - 1; ++t) {
    waitcnt_vm<4 * NSUB>();          // own stage(t) retired; stage(t+1) rides
    __builtin_amdgcn_s_barrier();    // => all waves' stage(t) complete
    compute(b0);
    __builtin_amdgcn_sched_barrier(0);
    __builtin_amdgcn_s_barrier();    // all waves done reading b0
    if (t + 2 < nt) stage((t + 2) * BK, b0);
    unsigned short* tmp = b0; b0 = b1; b1 = tmp;
  }
  waitcnt_vm<0>();                   // final tile: drain
  __builtin_amdgcn_s_barrier();
  compute(b0);
  __syncthreads();                   // LDS safe for caller epilogue reuse
}

// ---------------- weight fp32 -> bf16 (vectorized) -----------------------
struct WArgs { const float* src[6]; unsigned short* dst[6]; };
__global__ __launch_bounds__(256) void k_cvtw(WArgs a) {
  int z = blockIdx.y;
  int i = (blockIdx.x * 256 + threadIdx.x) << 3;
  const float* s = a.src[z] + i;
  float4 v0 = *(const float4*)s;
  float4 v1 = *(const float4*)(s + 4);
  unsigned short pk[8] = {f2bf(v0.x), f2bf(v0.y), f2bf(v0.z), f2bf(v0.w),
                          f2bf(v1.x), f2bf(v1.y), f2bf(v1.z), f2bf(v1.w)};
  *(int4*)(a.dst[z] + i) = *(int4*)pk;
}

// ---------------- transpose+convert: x[b][c][n] f32 -> Xt[b][n][c] bf16 --
// 64n x 32c tile: float4 coalesced reads -> f32 LDS (stride 68: 16B-aligned
// float4 stores) -> 8 scalar LDS reads (4-way bank = 1.58x, acceptable) ->
// packed int4 bf16x8 stores (wave writes 1 KB in optimal 32B sectors).
struct TArgs { const float* src[4]; unsigned short* dst[4]; };
__global__ __launch_bounds__(256) void k_tcvt(TArgs a) {
  __shared__ float tile[32][68];
  int z = blockIdx.z;  // array*2 + b
  const float* src = a.src[z >> 1] + (size_t)(z & 1) * (512 * 4096);
  unsigned short* dst = a.dst[z >> 1] + (size_t)(z & 1) * (4096 * 512);
  int n0 = blockIdx.x << 6;  // 64 n
  int c0 = blockIdx.y << 5;  // 32 c
  int tid = threadIdx.x;
  int q = tid & 15, r0 = tid >> 4;  // 16 lanes/row, 16 c-rows/pass
#pragma unroll
  for (int pass = 0; pass < 2; ++pass) {
    int r = r0 + (pass << 4);
    *(float4*)&tile[r][q << 2] =
        *(const float4*)(src + (size_t)(c0 + r) * 4096 + n0 + (q << 2));
  }
  __syncthreads();
  int j = tid >> 2, c8 = (tid & 3) << 3;  // n row j, 8 c's per thread
  unsigned short pk[8];
#pragma unroll
  for (int k = 0; k < 8; ++k) pk[k] = f2bf(tile[c8 + k][j]);
  *(int4*)(dst + (size_t)(n0 + j) * 512 + c0 + c8) = *(int4*)pk;
}

// ---------------- conv1x1 GEMMs: Y = W X^T + bias ------------------------
// trans=1 (Q,K): operand-swapped -> rows=n (A=X), cols=o (B=W); store
// out[n][o] with o in the lane dim. trans=0 (V): rows=o, cols=n.
struct ConvArgs {
  const unsigned short* W[12];
  const unsigned short* X[12];
  const float* bias[12];
  unsigned short* out[12];
  int trans[12];
};
__global__ __launch_bounds__(256) void k_conv(ConvArgs a) {
  __shared__ unsigned short sh[16384];  // 2 buf x (A 4K + B 4K shorts) = 32 KB
  int z = blockIdx.z;
  int trans = a.trans[z];
  int rowbase = (trans ? blockIdx.x : blockIdx.y) << 7;
  int colbase = (trans ? blockIdx.y : blockIdx.x) << 7;
  const unsigned short* Ag = trans ? a.X[z] : a.W[z];
  const unsigned short* Bg = trans ? a.W[z] : a.X[z];
  f32x4 acc[4][4];
#pragma unroll
  for (int i = 0; i < 4; ++i)
#pragma unroll
    for (int j = 0; j < 4; ++j) acc[i][j] = (f32x4){0.f, 0.f, 0.f, 0.f};
  gemm_core<1>(Ag, Bg, 512, 512, 512, rowbase, colbase, acc, sh);

  const int tid = threadIdx.x, w = tid >> 6, lane = tid & 63;
  const int quad = lane >> 4, l16 = lane & 15;
  const int wm = (w >> 1) << 6, wn = (w & 1) << 6;
  const float* bias = a.bias[z];
  unsigned short* out = a.out[z];
  if (trans) {
    float bo[4];
#pragma unroll
    for (int j = 0; j < 4; ++j) bo[j] = bias[colbase + wn + (j << 4) + l16];
#pragma unroll
    for (int i = 0; i < 4; ++i) {
      int n0 = rowbase + wm + (i << 4) + (quad << 2);
#pragma unroll
      for (int j = 0; j < 4; ++j) {
        int o = colbase + wn + (j << 4) + l16;
        out[(size_t)(n0 + 0) * 512 + o] = f2bf(acc[i][j].x + bo[j]);
        out[(size_t)(n0 + 1) * 512 + o] = f2bf(acc[i][j].y + bo[j]);
        out[(size_t)(n0 + 2) * 512 + o] = f2bf(acc[i][j].z + bo[j]);
        out[(size_t)(n0 + 3) * 512 + o] = f2bf(acc[i][j].w + bo[j]);
      }
    }
  } else {
#pragma unroll
    for (int i = 0; i < 4; ++i) {
      int o0 = rowbase + wm + (i << 4) + (quad << 2);
      float b0 = bias[o0], b1 = bias[o0 + 1], b2 = bias[o0 + 2], b3 = bias[o0 + 3];
#pragma unroll
      for (int j = 0; j < 4; ++j) {
        int n = colbase + wn + (j << 4) + l16;
        out[(size_t)(o0 + 0) * 4096 + n] = f2bf(acc[i][j].x + b0);
        out[(size_t)(o0 + 1) * 4096 + n] = f2bf(acc[i][j].y + b1);
        out[(size_t)(o0 + 2) * 4096 + n] = f2bf(acc[i][j].z + b2);
        out[(size_t)(o0 + 3) * 4096 + n] = f2bf(acc[i][j].w + b3);
      }
    }
  }
}

// ---------------- Et[n][m] = exp(Qt Kt^T), fused partial sum S[m] --------
// OPERAND-SWAPPED: A=Qt (rows=n), B=Kt (cols=m) -> m is the lane dim.
// 256x256 tile, 8 waves (wave grid 2r x 4c, wave tile 128x64), BK=32.
// LDS: 2 buf x (A 256x32 + B 256x32) = 64 KB. Counted-vmcnt pipeline.
// Plain grid mapping (r3 best; XCD remap reverted).
struct QKArgs {
  const unsigned short* Q[4]; const unsigned short* K[4]; unsigned short* T[4];
  float* pz;  // [4 z][16 nblk][4096 m] partial sums
};
__global__ __launch_bounds__(512) void k_qk(QKArgs a) {
  __shared__ unsigned short sh[32768];  // 64 KB
  int z = blockIdx.z;
  int nbase = blockIdx.y << 8;  // 256 rows = n
  int mbase = blockIdx.x << 8;  // 256 cols = m
  const unsigned short* Ag = a.Q[z];
  const unsigned short* Bg = a.K[z];

  const int tid = threadIdx.x;
  const int w = tid >> 6, lane = tid & 63;
  const int quad = lane >> 4, l16 = lane & 15;
  const int wr = w >> 2, wc = w & 3;
  const int wm = wr << 7;       // wave A-row base (0/128)
  const int wn = wc << 6;       // wave B-row base (0/64/128/192)
  const int rbase = (w << 5) + (lane >> 2);

  f32x4 acc[8][4];
#pragma unroll
  for (int i = 0; i < 8; ++i)
#pragma unroll
    for (int j = 0; j < 4; ++j) acc[i][j] = (f32x4){0.f, 0.f, 0.f, 0.f};

  auto stage = [&](int k0, unsigned short* buf) {
    unsigned short* Ah = buf;
    unsigned short* Bh = buf + 8192;
#pragma unroll
    for (int i = 0; i < 2; ++i) {
      int rloc = rbase + (i << 4);
      int cg = (lane & 3) ^ ((rloc >> 1) & 3);
      int koff = k0 + (cg << 3);
      int ldsoff = ((w << 5) + (i << 4)) << 5;
      async_copy16(Ag + (size_t)(nbase + rloc) * 512 + koff, Ah + ldsoff);
      async_copy16(Bg + (size_t)(mbase + rloc) * 512 + koff, Bh + ldsoff);
    }
  };

  auto compute = [&](const unsigned short* buf) {
    const unsigned short* Ah = buf;
    const unsigned short* Bh = buf + 8192;
    bf16x8 af[8], bfr[4];
#pragma unroll
    for (int i = 0; i < 8; ++i) {
      int r = wm + (i << 4) + l16;
      af[i] = *(const bf16x8*)(Ah + (r << 5) + ((quad ^ ((r >> 1) & 3)) << 3));
    }
#pragma unroll
    for (int j = 0; j < 4; ++j) {
      int r = wn + (j << 4) + l16;
      bfr[j] = *(const bf16x8*)(Bh + (r << 5) + ((quad ^ ((r >> 1) & 3)) << 3));
    }
#pragma unroll
    for (int i = 0; i < 8; ++i)
#pragma unroll
      for (int j = 0; j < 4; ++j)
        acc[i][j] = __builtin_amdgcn_mfma_f32_16x16x32_bf16(af[i], bfr[j], acc[i][j], 0, 0, 0);
  };

  unsigned short* b0 = sh;
  unsigned short* b1 = sh + 16384;
  stage(0, b0);
  stage(32, b1);
  for (int t = 0; t < 15; ++t) {
    waitcnt_vm<4>();
    __builtin_amdgcn_s_barrier();
    compute(b0);
    __builtin_amdgcn_sched_barrier(0);
    __builtin_amdgcn_s_barrier();
    if (t + 2 < 16) stage((t + 2) << 5, b0);
    unsigned short* tmp = b0; b0 = b1; b1 = tmp;
  }
  waitcnt_vm<0>();
  __builtin_amdgcn_s_barrier();
  compute(b0);
  __syncthreads();

  unsigned short* T = a.T[z];
  float sjv[4] = {0.f, 0.f, 0.f, 0.f};
#pragma unroll
  for (int i = 0; i < 8; ++i) {
    int n0 = nbase + wm + (i << 4) + (quad << 2);
#pragma unroll
    for (int j = 0; j < 4; ++j) {
      int m = mbase + wn + (j << 4) + l16;
      float e0 = __expf(acc[i][j].x);
      float e1 = __expf(acc[i][j].y);
      float e2 = __expf(acc[i][j].z);
      float e3 = __expf(acc[i][j].w);
      T[(size_t)(n0 + 0) * 4096 + m] = f2bf(e0);
      T[(size_t)(n0 + 1) * 4096 + m] = f2bf(e1);
      T[(size_t)(n0 + 2) * 4096 + m] = f2bf(e2);
      T[(size_t)(n0 + 3) * 4096 + m] = f2bf(e3);
      sjv[j] += e0 + e1 + e2 + e3;
    }
  }
  float* red = (float*)sh;  // [8 waves][64 m-local]
#pragma unroll
  for (int j = 0; j < 4; ++j) {
    float s = sjv[j];
    s += __shfl_xor(s, 16, 64);
    s += __shfl_xor(s, 32, 64);
    if (quad == 0) red[(w << 6) + (j << 4) + l16] = s;
  }
  __syncthreads();
  if (tid < 256) {
    // wave (wr=0) slot == tid, wave (wr=1) slot == tid + 256
    float S = red[tid] + red[tid + 256];
    a.pz[((z << 4) + blockIdx.y) * 4096 + mbase + tid] = S;
  }
}

// ---------------- merge 16 partials -> c[m] = 1/S ------------------------
__global__ __launch_bounds__(256) void k_stats2(const float* __restrict__ pz,
                                                float* __restrict__ c) {
  int m = (blockIdx.x << 8) + threadIdx.x;
  int z = blockIdx.y;
  float S = 0.f;
#pragma unroll
  for (int k = 0; k < 16; ++k) S += pz[((z << 4) + k) * 4096 + m];
  c[z * 4096 + m] = 1.f / S;
}

// ---------------- V'[c][m] = V[c][m] * c[m] (in place) -------------------
struct VSArgs { unsigned short* V[4]; const float* c; };
__global__ __launch_bounds__(256) void k_vscale(VSArgs a) {
  int z = blockIdx.y;
  int t = blockIdx.x * 256 + threadIdx.x;
  int m0 = (t & 511) << 3;
  int row = t >> 9;
  unsigned short* p = a.V[z] + (size_t)row * 4096 + m0;
  const float* cz = a.c + z * 4096 + m0;
  int4 raw = *(const int4*)p;
  unsigned short* u = (unsigned short*)&raw;
#pragma unroll
  for (int j = 0; j < 8; ++j) u[j] = f2bf(bf2f(u[j]) * cz[j]);
  *(int4*)p = raw;
}

// ---------------- O = V' E, epilogue relu(gamma*O + resid) ---------------
// Tc=256 (A=V' rows) x Tn=128 (B=E rows), BK=64 (2 subs of 32), 8 waves,
// wave grid 4c x 2n, wave tile 64x64, acc[4][4]. LDS 96 KB = 2 buf x
// (A 256x64 + B 128x64). Grid 256 blocks = exact fill. E read 2x/z = 268
// MB L3; V' read 32x -> L2-pinned: x = cb + 2z + 8nb => XCD = 2z+cb, all
// 32 blocks of an XCD share one 2 MB V' slice. Fine-phase schedule = r5's
// proven structure (fragment regs one phase ahead, counted vmcnt(6),
// setprio, lgkm(0) only before buffer overwrite).
struct PVArgs {
  const unsigned short* V[4];
  const unsigned short* P[4];  // Et[n][m]
  const float* resid[4];
  const float* gamma[4];
  float* out[4];
};
__global__ __launch_bounds__(512) void k_pv(PVArgs a) {
  __shared__ unsigned short sh[49152];  // 96 KB
  int x = blockIdx.x;           // x = cb + 2z + 8nb -> XCD = x&7 = 2z+cb
  int cb = x & 1;
  int z  = (x >> 1) & 3;
  int nb = x >> 3;              // 0..31
  int cbase = cb << 8;          // 256 c rows
  int nbase = nb << 7;          // 128 n rows
  const unsigned short* Ag = a.V[z];   // V'[c][m], stride 4096
  const unsigned short* Bg = a.P[z];   // E[n][m],  stride 4096

  const int tid = threadIdx.x;
  const int w = tid >> 6, lane = tid & 63;
  const int quad = lane >> 4, l16 = lane & 15;
  const int wm = (w >> 1) << 6;   // c offset 0/64/128/192
  const int wn = (w & 1) << 6;    // n offset 0/64

  f32x4 acc[4][4];
#pragma unroll
  for (int i = 0; i < 4; ++i)
#pragma unroll
    for (int j = 0; j < 4; ++j) acc[i][j] = (f32x4){0.f, 0.f, 0.f, 0.f};

  // Buffer layout (shorts), stride 24576 (48 KB):
  //   A s0 [0,8192) = 256r x 32k;  A s1 [8192,16384)
  //   B s0 [16384,20480) = 128r x 32k;  B s1 [20480,24576)
  // Chunk slot = chunk ^ ((row>>1)&3); source pre-swizzled, dest linear.
  const int srow = tid >> 2;                       // 0..127
  const int scg  = (tid & 3) ^ ((srow >> 1) & 3);
  auto stageTile = [&](int k0, unsigned short* buf) {
#pragma unroll
    for (int s = 0; s < 2; ++s) {
      int koff = k0 + (s << 5) + (scg << 3);
      unsigned short* As = buf + (s << 13);
      unsigned short* Bs = buf + 16384 + (s << 12);
      async_copy16(Ag + (size_t)(cbase + srow) * 4096 + koff, As + (w << 9));
      async_copy16(Ag + (size_t)(cbase + 128 + srow) * 4096 + koff,
                   As + 4096 + (w << 9));
      async_copy16(Bg + (size_t)(nbase + srow) * 4096 + koff, Bs + (w << 9));
    }
  };

  auto rdfrag = [&](const unsigned short* buf, int s, bf16x8 (&af)[4],
                    bf16x8 (&bfr)[4]) {
    const unsigned short* As = buf + (s << 13);
    const unsigned short* Bs = buf + 16384 + (s << 12);
#pragma unroll
    for (int i = 0; i < 4; ++i) {
      int r = wm + (i << 4) + l16;    // 0..255
      af[i] = *(const bf16x8*)(As + (r << 5) + ((quad ^ ((r >> 1) & 3)) << 3));
    }
#pragma unroll
    for (int j = 0; j < 4; ++j) {
      int r = wn + (j << 4) + l16;    // 0..127
      bfr[j] = *(const bf16x8*)(Bs + (r << 5) + ((quad ^ ((r >> 1) & 3)) << 3));
    }
  };

  auto mfma16 = [&](bf16x8 (&af)[4], bf16x8 (&bfr)[4]) {
#pragma unroll
    for (int i = 0; i < 4; ++i)
#pragma unroll
      for (int j = 0; j < 4; ++j)
        acc[i][j] = __builtin_amdgcn_mfma_f32_16x16x32_bf16(af[i], bfr[j], acc[i][j], 0, 0, 0);
  };

  unsigned short* b0 = sh;
  unsigned short* b1 = sh + 24576;

  bf16x8 afA[4], bfA[4], afB[4], bfB[4];

  stageTile(0, b0);
  stageTile(64, b1);
  waitcnt_vm<6>();                     // buf0's 6 loads done, buf1's ride
  __builtin_amdgcn_s_barrier();
  rdfrag(b0, 0, afA, bfA);             // tile0.sub0 -> set A (in flight)

  for (int t = 0; t < 63; ++t) {
    unsigned short* cur = (t & 1) ? b1 : b0;
    unsigned short* nxt = (t & 1) ? b0 : b1;
    // PHASE A: read cur.sub1 || MFMA set A (compiler waits set A's lgkm)
    rdfrag(cur, 1, afB, bfB);
    __builtin_amdgcn_s_setprio(1);
    mfma16(afA, bfA);
    __builtin_amdgcn_s_setprio(0);
    asm volatile("s_waitcnt lgkmcnt(0)" ::: "memory");  // cur fully consumed
    __builtin_amdgcn_s_barrier();
    // PHASE B: restage cur for t+2; wait tile t+1 landed; read nxt.sub0 ||
    // MFMA set B.
    if (t + 2 < 64) {
      stageTile((t + 2) << 6, cur);
      waitcnt_vm<6>();                 // stage(t+1) retired, stage(t+2) rides
    } else {
      waitcnt_vm<0>();                 // tail: drain stage(63)
    }
    __builtin_amdgcn_s_barrier();
    rdfrag(nxt, 0, afA, bfA);
    __builtin_amdgcn_s_setprio(1);
    mfma16(afB, bfB);
    __builtin_amdgcn_s_setprio(0);
  }
  // t = 63: cur = b1; set A holds tile63.sub0 (read in t=62 phase B).
  rdfrag(b1, 1, afB, bfB);
  mfma16(afA, bfA);
  mfma16(afB, bfB);

  float g = a.gamma[z][0];
  const float* R = a.resid[z];
  float* O = a.out[z];
#pragma unroll
  for (int i = 0; i < 4; ++i) {
    int c0 = cbase + wm + (i << 4) + (quad << 2);
#pragma unroll
    for (int j = 0; j < 4; ++j) {
      int n = nbase + wn + (j << 4) + l16;
      O[(size_t)(c0 + 0) * 4096 + n] = fmaxf(g * acc[i][j].x + R[(size_t)(c0 + 0) * 4096 + n], 0.f);
      O[(size_t)(c0 + 1) * 4096 + n] = fmaxf(g * acc[i][j].y + R[(size_t)(c0 + 1) * 4096 + n], 0.f);
      O[(size_t)(c0 + 2) * 4096 + n] = fmaxf(g * acc[i][j].z + R[(size_t)(c0 + 2) * 4096 + n], 0.f);
      O[(size_t)(c0 + 3) * 4096 + n] = fmaxf(g * acc[i][j].w + R[(size_t)(c0 + 3) * 4096 + n], 0.f);
    }
  }
}

// ---------------------------------------------------------------------------
extern "C" void kernel_launch(void* const* d_in, const int* in_sizes, int n_in,
                              void* d_out, int out_size, void* d_ws, size_t ws_size,
                              hipStream_t stream) {
  char* ws = (char*)d_ws;
  unsigned short* wb  = (unsigned short*)(ws);              //  6 x 512x512 bf16
  unsigned short* xt  = (unsigned short*)(ws + 3145728);    //  4 x [2][4096][512]
  unsigned short* qkv = (unsigned short*)(ws + 36700160);   // 12 x [4096x512]
  unsigned short* tt  = (unsigned short*)(ws + 87031808);   //  4 x [4096x4096]
  float* pz  = (float*)(ws + 3145728);                      // overlaps dead xt
  float* cb  = (float*)(ws + 3145728 + 2097152);

  // 1. weights -> bf16
  WArgs wa;
  for (int i = 0; i < 6; ++i) {
    wa.src[i] = (const float*)d_in[4 + 2 * i];
    wa.dst[i] = wb + (size_t)i * 262144;
  }
  k_cvtw<<<dim3(128, 6), 256, 0, stream>>>(wa);

  // 2. feature maps -> transposed bf16 Xt[b][n][c]
  TArgs ta;
  for (int ai = 0; ai < 4; ++ai) {
    ta.src[ai] = (const float*)d_in[ai];
    ta.dst[ai] = xt + (size_t)ai * 4194304;
  }
  k_tcvt<<<dim3(64, 16, 8), 256, 0, stream>>>(ta);

  // 3. six convs x two batches (q_rd, k_rd, v_rd, q_dr, k_dr, v_dr)
  const int srcArr[6] = {2, 0, 3, 3, 1, 1};
  const int trans[6] = {1, 1, 0, 1, 1, 0};
  ConvArgs ca;
  for (int ci = 0; ci < 6; ++ci)
    for (int b = 0; b < 2; ++b) {
      int zz = ci * 2 + b;
      ca.W[zz] = wb + (size_t)ci * 262144;
      ca.X[zz] = xt + (size_t)srcArr[ci] * 4194304 + (size_t)b * 2097152;
      ca.bias[zz] = (const float*)d_in[5 + 2 * ci];
      ca.out[zz] = qkv + (size_t)zz * 2097152;
      ca.trans[zz] = trans[ci];
    }
  k_conv<<<dim3(32, 4, 12), 256, 0, stream>>>(ca);

  // 4. Et[n][m] = exp(Qt Kt^T) + fused partial sums (256^2 tile, 8 waves)
  QKArgs qa;
  for (int path = 0; path < 2; ++path)
    for (int b = 0; b < 2; ++b) {
      int zz = path * 2 + b;
      qa.Q[zz] = qkv + (size_t)((path * 3 + 0) * 2 + b) * 2097152;  // Qt (rows=n)
      qa.K[zz] = qkv + (size_t)((path * 3 + 1) * 2 + b) * 2097152;  // Kt (cols=m)
      qa.T[zz] = tt + (size_t)zz * 16777216;
    }
  qa.pz = pz;
  k_qk<<<dim3(16, 16, 4), 512, 0, stream>>>(qa);

  // 5. merge partials -> c[m] = 1/S
  k_stats2<<<dim3(16, 4), 256, 0, stream>>>(pz, cb);

  // 6. V' = V * c[m]
  VSArgs va;
  for (int path = 0; path < 2; ++path)
    for (int b = 0; b < 2; ++b)
      va.V[path * 2 + b] = qkv + (size_t)((path * 3 + 2) * 2 + b) * 2097152;
  va.c = cb;
  k_vscale<<<dim3(1024, 4), 256, 0, stream>>>(va);

  // 7. O = V' E + fused epilogue (Tc=256 x Tn=128, BK=64, fine-phase,
  //    full fill, XCD-pinned V')
  PVArgs pa;
  const float* resid_src[2] = {(const float*)d_in[2], (const float*)d_in[3]};
  const float* gsrc[2] = {(const float*)d_in[16], (const float*)d_in[17]};
  for (int path = 0; path < 2; ++path)
    for (int b = 0; b < 2; ++b) {
      int zz = path * 2 + b;
      pa.V[zz] = qkv + (size_t)((path * 3 + 2) * 2 + b) * 2097152;
      pa.P[zz] = tt + (size_t)zz * 16777216;
      pa.resid[zz] = resid_src[path] + (size_t)b * 2097152;
      pa.gamma[zz] = gsrc[path];
      pa.out[zz] = (float*)d_out + (size_t)zz * 2097152;
    }
  k_pv<<<dim3(256), 512, 0, stream>>>(pa);
}

// Round 8
// 369.752 us; speedup vs baseline: 1.1311x; 1.0428x over previous
//
#include <hip/hip_runtime.h>
#include <stdint.h>

// ---------------------------------------------------------------------------
// FeatureMapTransformer: dual cross-attention (rd / dr paths), B=2, C=512,
// H=W=64 -> N=M=4096.
//   Qt[n][c], Kt[m][c] (transposed conv outs), V[c][m]        (bf16)
//   Et[n][m] = bf16(exp(sum_c Kt[m][c] Qt[n][c]))             (k_qk)
//   partial S[m] = sum_n exp(T) fused into k_qk -> c[m] = 1/S (k_stats2)
//   V'[c][m] = V[c][m] * c[m]                                 (k_vscale)
//   O[c][n]  = sum_m V'[c][m] E[n][m]  (pure bf16 GEMM)       (k_pv)
//   out = relu(gamma*O + resid)  (fused k_pv epilogue)
// HISTORY: E-L3-stream model DISPROVEN in r7 -- r3 (536 MB E-stream, 2
// blk/CU), r5 (536 MB, fine-phase), r7 (268 MB, XCD-pinned V') all land
// at 108-110 us. k_pv is invariant to traffic volume/tile aspect.
// Round-18 theory: LATENCY, not bandwidth. 109 us / 64 K-steps = 3580
// cyc/iter vs ~512 cyc MFMA work. All variants had lookahead = 1 tile:
// stage(t+1) issues in iter t-1 phase B and must land by iter t phase B
// -- only ~500-800 cyc of cover vs ~900-2500 cyc congested load latency.
// Barrier-locked 1-block/CU => whole CU stalls at vmcnt every iteration.
// Fix: TRIPLE BUFFER (lookahead 2 tiles, ~7000 cyc cover). LDS 3 x 48 KB
// = 144 KB (< 160). Phase B restages t+3, waits vmcnt(12) (newest 2
// stages ride). Exact tail counts at t=61/62. Rotating pointer triple
// (scalar swap -- no runtime-indexed array, rule-20). Geometry/stage/
// rdfrag/frag-pipeline identical to r7 (single-variable experiment).
// ---------------------------------------------------------------------------

typedef __attribute__((ext_vector_type(8))) __bf16 bf16x8;
typedef __attribute__((ext_vector_type(4))) float f32x4;

__device__ __forceinline__ unsigned short f2bf(float f) {
  union { float f; unsigned u; } v; v.f = f;
  unsigned r = v.u + 0x7FFFu + ((v.u >> 16) & 1u);
  return (unsigned short)(r >> 16);
}
__device__ __forceinline__ float bf2f(unsigned short b) {
  union { unsigned u; float f; } v; v.u = ((unsigned)b) << 16;
  return v.f;
}

__device__ __forceinline__ void async_copy16(const unsigned short* g,
                                             unsigned short* l) {
  __builtin_amdgcn_global_load_lds(
      (const __attribute__((address_space(1))) unsigned int*)g,
      (__attribute__((address_space(3))) unsigned int*)l, 16, 0, 0);
}

// Counted VMEM wait (literal immediates only). Memory clobber pins all
// memory ops (ds_read / global_load_lds) on the correct side.
template <int N>
__device__ __forceinline__ void waitcnt_vm() {
  if constexpr (N == 0) asm volatile("s_waitcnt vmcnt(0)" ::: "memory");
  else if constexpr (N == 4) asm volatile("s_waitcnt vmcnt(4)" ::: "memory");
  else if constexpr (N == 6) asm volatile("s_waitcnt vmcnt(6)" ::: "memory");
  else if constexpr (N == 8) asm volatile("s_waitcnt vmcnt(8)" ::: "memory");
  else asm volatile("s_waitcnt vmcnt(12)" ::: "memory");
}

// C[128x128 at (rowbase,colbase)] += A[row][k] * B[col][k]^T, K-contig A/B.
// lds layout: [2 buffers][A|B][NSUB][128x32 sub-tile = 4096 shorts].
// 16B chunk c of row r lives at slot c^((r>>1)&3) (pre-swizzled on the
// global source side; global_load_lds dest stays linear).
template <int NSUB>
__device__ __forceinline__ void gemm_core(
    const unsigned short* __restrict__ Ag, const unsigned short* __restrict__ Bg,
    int K, int lda, int ldb, int rowbase, int colbase,
    f32x4 (&acc)[4][4], unsigned short* lds) {
  const int tid = threadIdx.x;
  const int w = tid >> 6, lane = tid & 63;
  const int quad = lane >> 4, l16 = lane & 15;
  const int wm = (w >> 1) << 6, wn = (w & 1) << 6;
  const int rbase = (w << 5) + (lane >> 2);
  const int BK = 32 * NSUB;

  auto stage = [&](int k0, unsigned short* buf) {
#pragma unroll
    for (int half = 0; half < NSUB; ++half) {
      int kh = k0 + (half << 5);
      unsigned short* Ah = buf + (half << 12);
      unsigned short* Bh = buf + (NSUB << 12) + (half << 12);
#pragma unroll
      for (int i = 0; i < 2; ++i) {
        int rloc = rbase + (i << 4);
        int cg = (lane & 3) ^ ((rloc >> 1) & 3);
        int koff = kh + (cg << 3);
        int ldsoff = ((w << 5) + (i << 4)) << 5;
        async_copy16(Ag + (size_t)(rowbase + rloc) * lda + koff, Ah + ldsoff);
        async_copy16(Bg + (size_t)(colbase + rloc) * ldb + koff, Bh + ldsoff);
      }
    }
  };

  auto compute = [&](const unsigned short* buf) {
#pragma unroll
    for (int half = 0; half < NSUB; ++half) {
      const unsigned short* Ah = buf + (half << 12);
      const unsigned short* Bh = buf + (NSUB << 12) + (half << 12);
      bf16x8 af[4], bfr[4];
#pragma unroll
      for (int i = 0; i < 4; ++i) {
        int r = wm + (i << 4) + l16;
        af[i] = *(const bf16x8*)(Ah + (r << 5) + ((quad ^ ((r >> 1) & 3)) << 3));
      }
#pragma unroll
      for (int j = 0; j < 4; ++j) {
        int r = wn + (j << 4) + l16;
        bfr[j] = *(const bf16x8*)(Bh + (r << 5) + ((quad ^ ((r >> 1) & 3)) << 3));
      }
#pragma unroll
      for (int i = 0; i < 4; ++i)
#pragma unroll
        for (int j = 0; j < 4; ++j)
          acc[i][j] = __builtin_amdgcn_mfma_f32_16x16x32_bf16(af[i], bfr[j], acc[i][j], 0, 0, 0);
    }
  };

  unsigned short* b0 = lds;                   // current compute buffer
  unsigned short* b1 = lds + (NSUB << 13);    // in-flight prefetch buffer
  const int nt = K / BK;

  stage(0, b0);
  stage(BK, b1);
  for (int t = 0; t < nt - 1; ++t) {
    waitcnt_vm<4 * NSUB>();          // own stage(t) retired; stage(t+1) rides
    __builtin_amdgcn_s_barrier();    // => all waves' stage(t) complete
    compute(b0);
    __builtin_amdgcn_sched_barrier(0);
    __builtin_amdgcn_s_barrier();    // all waves done reading b0
    if (t + 2 < nt) stage((t + 2) * BK, b0);
    unsigned short* tmp = b0; b0 = b1; b1 = tmp;
  }
  waitcnt_vm<0>();                   // final tile: drain
  __builtin_amdgcn_s_barrier();
  compute(b0);
  __syncthreads();                   // LDS safe for caller epilogue reuse
}

// ---------------- weight fp32 -> bf16 (vectorized) -----------------------
struct WArgs { const float* src[6]; unsigned short* dst[6]; };
__global__ __launch_bounds__(256) void k_cvtw(WArgs a) {
  int z = blockIdx.y;
  int i = (blockIdx.x * 256 + threadIdx.x) << 3;
  const float* s = a.src[z] + i;
  float4 v0 = *(const float4*)s;
  float4 v1 = *(const float4*)(s + 4);
  unsigned short pk[8] = {f2bf(v0.x), f2bf(v0.y), f2bf(v0.z), f2bf(v0.w),
                          f2bf(v1.x), f2bf(v1.y), f2bf(v1.z), f2bf(v1.w)};
  *(int4*)(a.dst[z] + i) = *(int4*)pk;
}

// ---------------- transpose+convert: x[b][c][n] f32 -> Xt[b][n][c] bf16 --
// 64n x 32c tile: float4 coalesced reads -> f32 LDS (stride 68: 16B-aligned
// float4 stores) -> 8 scalar LDS reads (4-way bank = 1.58x, acceptable) ->
// packed int4 bf16x8 stores (wave writes 1 KB in optimal 32B sectors).
struct TArgs { const float* src[4]; unsigned short* dst[4]; };
__global__ __launch_bounds__(256) void k_tcvt(TArgs a) {
  __shared__ float tile[32][68];
  int z = blockIdx.z;  // array*2 + b
  const float* src = a.src[z >> 1] + (size_t)(z & 1) * (512 * 4096);
  unsigned short* dst = a.dst[z >> 1] + (size_t)(z & 1) * (4096 * 512);
  int n0 = blockIdx.x << 6;  // 64 n
  int c0 = blockIdx.y << 5;  // 32 c
  int tid = threadIdx.x;
  int q = tid & 15, r0 = tid >> 4;  // 16 lanes/row, 16 c-rows/pass
#pragma unroll
  for (int pass = 0; pass < 2; ++pass) {
    int r = r0 + (pass << 4);
    *(float4*)&tile[r][q << 2] =
        *(const float4*)(src + (size_t)(c0 + r) * 4096 + n0 + (q << 2));
  }
  __syncthreads();
  int j = tid >> 2, c8 = (tid & 3) << 3;  // n row j, 8 c's per thread
  unsigned short pk[8];
#pragma unroll
  for (int k = 0; k < 8; ++k) pk[k] = f2bf(tile[c8 + k][j]);
  *(int4*)(dst + (size_t)(n0 + j) * 512 + c0 + c8) = *(int4*)pk;
}

// ---------------- conv1x1 GEMMs: Y = W X^T + bias ------------------------
// trans=1 (Q,K): operand-swapped -> rows=n (A=X), cols=o (B=W); store
// out[n][o] with o in the lane dim. trans=0 (V): rows=o, cols=n.
struct ConvArgs {
  const unsigned short* W[12];
  const unsigned short* X[12];
  const float* bias[12];
  unsigned short* out[12];
  int trans[12];
};
__global__ __launch_bounds__(256) void k_conv(ConvArgs a) {
  __shared__ unsigned short sh[16384];  // 2 buf x (A 4K + B 4K shorts) = 32 KB
  int z = blockIdx.z;
  int trans = a.trans[z];
  int rowbase = (trans ? blockIdx.x : blockIdx.y) << 7;
  int colbase = (trans ? blockIdx.y : blockIdx.x) << 7;
  const unsigned short* Ag = trans ? a.X[z] : a.W[z];
  const unsigned short* Bg = trans ? a.W[z] : a.X[z];
  f32x4 acc[4][4];
#pragma unroll
  for (int i = 0; i < 4; ++i)
#pragma unroll
    for (int j = 0; j < 4; ++j) acc[i][j] = (f32x4){0.f, 0.f, 0.f, 0.f};
  gemm_core<1>(Ag, Bg, 512, 512, 512, rowbase, colbase, acc, sh);

  const int tid = threadIdx.x, w = tid >> 6, lane = tid & 63;
  const int quad = lane >> 4, l16 = lane & 15;
  const int wm = (w >> 1) << 6, wn = (w & 1) << 6;
  const float* bias = a.bias[z];
  unsigned short* out = a.out[z];
  if (trans) {
    float bo[4];
#pragma unroll
    for (int j = 0; j < 4; ++j) bo[j] = bias[colbase + wn + (j << 4) + l16];
#pragma unroll
    for (int i = 0; i < 4; ++i) {
      int n0 = rowbase + wm + (i << 4) + (quad << 2);
#pragma unroll
      for (int j = 0; j < 4; ++j) {
        int o = colbase + wn + (j << 4) + l16;
        out[(size_t)(n0 + 0) * 512 + o] = f2bf(acc[i][j].x + bo[j]);
        out[(size_t)(n0 + 1) * 512 + o] = f2bf(acc[i][j].y + bo[j]);
        out[(size_t)(n0 + 2) * 512 + o] = f2bf(acc[i][j].z + bo[j]);
        out[(size_t)(n0 + 3) * 512 + o] = f2bf(acc[i][j].w + bo[j]);
      }
    }
  } else {
#pragma unroll
    for (int i = 0; i < 4; ++i) {
      int o0 = rowbase + wm + (i << 4) + (quad << 2);
      float b0 = bias[o0], b1 = bias[o0 + 1], b2 = bias[o0 + 2], b3 = bias[o0 + 3];
#pragma unroll
      for (int j = 0; j < 4; ++j) {
        int n = colbase + wn + (j << 4) + l16;
        out[(size_t)(o0 + 0) * 4096 + n] = f2bf(acc[i][j].x + b0);
        out[(size_t)(o0 + 1) * 4096 + n] = f2bf(acc[i][j].y + b1);
        out[(size_t)(o0 + 2) * 4096 + n] = f2bf(acc[i][j].z + b2);
        out[(size_t)(o0 + 3) * 4096 + n] = f2bf(acc[i][j].w + b3);
      }
    }
  }
}

// ---------------- Et[n][m] = exp(Qt Kt^T), fused partial sum S[m] --------
// OPERAND-SWAPPED: A=Qt (rows=n), B=Kt (cols=m) -> m is the lane dim.
// 256x256 tile, 8 waves (wave grid 2r x 4c, wave tile 128x64), BK=32.
// LDS: 2 buf x (A 256x32 + B 256x32) = 64 KB. Counted-vmcnt pipeline.
struct QKArgs {
  const unsigned short* Q[4]; const unsigned short* K[4]; unsigned short* T[4];
  float* pz;  // [4 z][16 nblk][4096 m] partial sums
};
__global__ __launch_bounds__(512) void k_qk(QKArgs a) {
  __shared__ unsigned short sh[32768];  // 64 KB
  int z = blockIdx.z;
  int nbase = blockIdx.y << 8;  // 256 rows = n
  int mbase = blockIdx.x << 8;  // 256 cols = m
  const unsigned short* Ag = a.Q[z];
  const unsigned short* Bg = a.K[z];

  const int tid = threadIdx.x;
  const int w = tid >> 6, lane = tid & 63;
  const int quad = lane >> 4, l16 = lane & 15;
  const int wr = w >> 2, wc = w & 3;
  const int wm = wr << 7;       // wave A-row base (0/128)
  const int wn = wc << 6;       // wave B-row base (0/64/128/192)
  const int rbase = (w << 5) + (lane >> 2);

  f32x4 acc[8][4];
#pragma unroll
  for (int i = 0; i < 8; ++i)
#pragma unroll
    for (int j = 0; j < 4; ++j) acc[i][j] = (f32x4){0.f, 0.f, 0.f, 0.f};

  auto stage = [&](int k0, unsigned short* buf) {
    unsigned short* Ah = buf;
    unsigned short* Bh = buf + 8192;
#pragma unroll
    for (int i = 0; i < 2; ++i) {
      int rloc = rbase + (i << 4);
      int cg = (lane & 3) ^ ((rloc >> 1) & 3);
      int koff = k0 + (cg << 3);
      int ldsoff = ((w << 5) + (i << 4)) << 5;
      async_copy16(Ag + (size_t)(nbase + rloc) * 512 + koff, Ah + ldsoff);
      async_copy16(Bg + (size_t)(mbase + rloc) * 512 + koff, Bh + ldsoff);
    }
  };

  auto compute = [&](const unsigned short* buf) {
    const unsigned short* Ah = buf;
    const unsigned short* Bh = buf + 8192;
    bf16x8 af[8], bfr[4];
#pragma unroll
    for (int i = 0; i < 8; ++i) {
      int r = wm + (i << 4) + l16;
      af[i] = *(const bf16x8*)(Ah + (r << 5) + ((quad ^ ((r >> 1) & 3)) << 3));
    }
#pragma unroll
    for (int j = 0; j < 4; ++j) {
      int r = wn + (j << 4) + l16;
      bfr[j] = *(const bf16x8*)(Bh + (r << 5) + ((quad ^ ((r >> 1) & 3)) << 3));
    }
#pragma unroll
    for (int i = 0; i < 8; ++i)
#pragma unroll
      for (int j = 0; j < 4; ++j)
        acc[i][j] = __builtin_amdgcn_mfma_f32_16x16x32_bf16(af[i], bfr[j], acc[i][j], 0, 0, 0);
  };

  unsigned short* b0 = sh;
  unsigned short* b1 = sh + 16384;
  stage(0, b0);
  stage(32, b1);
  for (int t = 0; t < 15; ++t) {
    waitcnt_vm<4>();
    __builtin_amdgcn_s_barrier();
    compute(b0);
    __builtin_amdgcn_sched_barrier(0);
    __builtin_amdgcn_s_barrier();
    if (t + 2 < 16) stage((t + 2) << 5, b0);
    unsigned short* tmp = b0; b0 = b1; b1 = tmp;
  }
  waitcnt_vm<0>();
  __builtin_amdgcn_s_barrier();
  compute(b0);
  __syncthreads();

  unsigned short* T = a.T[z];
  float sjv[4] = {0.f, 0.f, 0.f, 0.f};
#pragma unroll
  for (int i = 0; i < 8; ++i) {
    int n0 = nbase + wm + (i << 4) + (quad << 2);
#pragma unroll
    for (int j = 0; j < 4; ++j) {
      int m = mbase + wn + (j << 4) + l16;
      float e0 = __expf(acc[i][j].x);
      float e1 = __expf(acc[i][j].y);
      float e2 = __expf(acc[i][j].z);
      float e3 = __expf(acc[i][j].w);
      T[(size_t)(n0 + 0) * 4096 + m] = f2bf(e0);
      T[(size_t)(n0 + 1) * 4096 + m] = f2bf(e1);
      T[(size_t)(n0 + 2) * 4096 + m] = f2bf(e2);
      T[(size_t)(n0 + 3) * 4096 + m] = f2bf(e3);
      sjv[j] += e0 + e1 + e2 + e3;
    }
  }
  float* red = (float*)sh;  // [8 waves][64 m-local]
#pragma unroll
  for (int j = 0; j < 4; ++j) {
    float s = sjv[j];
    s += __shfl_xor(s, 16, 64);
    s += __shfl_xor(s, 32, 64);
    if (quad == 0) red[(w << 6) + (j << 4) + l16] = s;
  }
  __syncthreads();
  if (tid < 256) {
    // wave (wr=0) slot == tid, wave (wr=1) slot == tid + 256
    float S = red[tid] + red[tid + 256];
    a.pz[((z << 4) + blockIdx.y) * 4096 + mbase + tid] = S;
  }
}

// ---------------- merge 16 partials -> c[m] = 1/S ------------------------
__global__ __launch_bounds__(256) void k_stats2(const float* __restrict__ pz,
                                                float* __restrict__ c) {
  int m = (blockIdx.x << 8) + threadIdx.x;
  int z = blockIdx.y;
  float S = 0.f;
#pragma unroll
  for (int k = 0; k < 16; ++k) S += pz[((z << 4) + k) * 4096 + m];
  c[z * 4096 + m] = 1.f / S;
}

// ---------------- V'[c][m] = V[c][m] * c[m] (in place) -------------------
struct VSArgs { unsigned short* V[4]; const float* c; };
__global__ __launch_bounds__(256) void k_vscale(VSArgs a) {
  int z = blockIdx.y;
  int t = blockIdx.x * 256 + threadIdx.x;
  int m0 = (t & 511) << 3;
  int row = t >> 9;
  unsigned short* p = a.V[z] + (size_t)row * 4096 + m0;
  const float* cz = a.c + z * 4096 + m0;
  int4 raw = *(const int4*)p;
  unsigned short* u = (unsigned short*)&raw;
#pragma unroll
  for (int j = 0; j < 8; ++j) u[j] = f2bf(bf2f(u[j]) * cz[j]);
  *(int4*)p = raw;
}

// ---------------- O = V' E, epilogue relu(gamma*O + resid) ---------------
// Tc=256 x Tn=128, BK=64 (2 subs of 32), 8 waves, wave tile 64x64,
// acc[4][4]. TRIPLE-BUFFERED: LDS 3 x 48 KB = 144 KB, lookahead 2 tiles
// (stage(t+3) issued at iter t; vmcnt(12) = newest 2 stages in flight).
// Grid 256 blocks = exact fill; x = cb + 2z + 8nb pins XCD = 2z+cb
// (V' slice L2-hot). Fine-phase frag pipeline as r5/r7.
struct PVArgs {
  const unsigned short* V[4];
  const unsigned short* P[4];  // Et[n][m]
  const float* resid[4];
  const float* gamma[4];
  float* out[4];
};
__global__ __launch_bounds__(512) void k_pv(PVArgs a) {
  __shared__ unsigned short sh[73728];  // 144 KB = 3 x 24576 shorts
  int x = blockIdx.x;           // x = cb + 2z + 8nb -> XCD = x&7 = 2z+cb
  int cb = x & 1;
  int z  = (x >> 1) & 3;
  int nb = x >> 3;              // 0..31
  int cbase = cb << 8;          // 256 c rows
  int nbase = nb << 7;          // 128 n rows
  const unsigned short* Ag = a.V[z];   // V'[c][m], stride 4096
  const unsigned short* Bg = a.P[z];   // E[n][m],  stride 4096

  const int tid = threadIdx.x;
  const int w = tid >> 6, lane = tid & 63;
  const int quad = lane >> 4, l16 = lane & 15;
  const int wm = (w >> 1) << 6;   // c offset 0/64/128/192
  const int wn = (w & 1) << 6;    // n offset 0/64

  f32x4 acc[4][4];
#pragma unroll
  for (int i = 0; i < 4; ++i)
#pragma unroll
    for (int j = 0; j < 4; ++j) acc[i][j] = (f32x4){0.f, 0.f, 0.f, 0.f};

  // Buffer layout (shorts), stride 24576 (48 KB):
  //   A s0 [0,8192) = 256r x 32k;  A s1 [8192,16384)
  //   B s0 [16384,20480) = 128r x 32k;  B s1 [20480,24576)
  // Chunk slot = chunk ^ ((row>>1)&3); source pre-swizzled, dest linear.
  const int srow = tid >> 2;                       // 0..127
  const int scg  = (tid & 3) ^ ((srow >> 1) & 3);
  auto stageTile = [&](int k0, unsigned short* buf) {
#pragma unroll
    for (int s = 0; s < 2; ++s) {
      int koff = k0 + (s << 5) + (scg << 3);
      unsigned short* As = buf + (s << 13);
      unsigned short* Bs = buf + 16384 + (s << 12);
      async_copy16(Ag + (size_t)(cbase + srow) * 4096 + koff, As + (w << 9));
      async_copy16(Ag + (size_t)(cbase + 128 + srow) * 4096 + koff,
                   As + 4096 + (w << 9));
      async_copy16(Bg + (size_t)(nbase + srow) * 4096 + koff, Bs + (w << 9));
    }
  };

  auto rdfrag = [&](const unsigned short* buf, int s, bf16x8 (&af)[4],
                    bf16x8 (&bfr)[4]) {
    const unsigned short* As = buf + (s << 13);
    const unsigned short* Bs = buf + 16384 + (s << 12);
#pragma unroll
    for (int i = 0; i < 4; ++i) {
      int r = wm + (i << 4) + l16;    // 0..255
      af[i] = *(const bf16x8*)(As + (r << 5) + ((quad ^ ((r >> 1) & 3)) << 3));
    }
#pragma unroll
    for (int j = 0; j < 4; ++j) {
      int r = wn + (j << 4) + l16;    // 0..127
      bfr[j] = *(const bf16x8*)(Bs + (r << 5) + ((quad ^ ((r >> 1) & 3)) << 3));
    }
  };

  auto mfma16 = [&](bf16x8 (&af)[4], bf16x8 (&bfr)[4]) {
#pragma unroll
    for (int i = 0; i < 4; ++i)
#pragma unroll
      for (int j = 0; j < 4; ++j)
        acc[i][j] = __builtin_amdgcn_mfma_f32_16x16x32_bf16(af[i], bfr[j], acc[i][j], 0, 0, 0);
  };

  unsigned short* p0 = sh;             // holds tile t
  unsigned short* p1 = sh + 24576;     // tile t+1
  unsigned short* p2 = sh + 49152;     // tile t+2

  bf16x8 afA[4], bfA[4], afB[4], bfB[4];

  stageTile(0, p0);
  stageTile(64, p1);
  stageTile(128, p2);
  waitcnt_vm<12>();                    // tile0's 6 loads done; 12 ride
  __builtin_amdgcn_s_barrier();
  rdfrag(p0, 0, afA, bfA);             // tile0.sub0 -> set A (in flight)

  for (int t = 0; t < 63; ++t) {
    // PHASE A: read p0.sub1 || MFMA set A (compiler waits set A's lgkm)
    rdfrag(p0, 1, afB, bfB);
    __builtin_amdgcn_s_setprio(1);
    mfma16(afA, bfA);
    __builtin_amdgcn_s_setprio(0);
    asm volatile("s_waitcnt lgkmcnt(0)" ::: "memory");  // p0 fully consumed
    __builtin_amdgcn_s_barrier();
    // PHASE B: restage p0 for tile t+3; ensure tile t+1 landed; read
    // p1.sub0 || MFMA set B.
    if (t <= 60) {
      stageTile((t + 3) << 6, p0);
      waitcnt_vm<12>();                // tile t+1 done; t+2,t+3 ride
    } else if (t == 61) {
      waitcnt_vm<6>();                 // tile 62 done; 63 rides
    } else {
      waitcnt_vm<0>();                 // tile 63 done
    }
    __builtin_amdgcn_s_barrier();
    rdfrag(p1, 0, afA, bfA);
    __builtin_amdgcn_s_setprio(1);
    mfma16(afB, bfB);
    __builtin_amdgcn_s_setprio(0);
    unsigned short* tmp = p0; p0 = p1; p1 = p2; p2 = tmp;
  }
  // After 63 rotations p0 holds tile 63; set A holds tile63.sub0.
  rdfrag(p0, 1, afB, bfB);
  mfma16(afA, bfA);
  mfma16(afB, bfB);

  float g = a.gamma[z][0];
  const float* R = a.resid[z];
  float* O = a.out[z];
#pragma unroll
  for (int i = 0; i < 4; ++i) {
    int c0 = cbase + wm + (i << 4) + (quad << 2);
#pragma unroll
    for (int j = 0; j < 4; ++j) {
      int n = nbase + wn + (j << 4) + l16;
      O[(size_t)(c0 + 0) * 4096 + n] = fmaxf(g * acc[i][j].x + R[(size_t)(c0 + 0) * 4096 + n], 0.f);
      O[(size_t)(c0 + 1) * 4096 + n] = fmaxf(g * acc[i][j].y + R[(size_t)(c0 + 1) * 4096 + n], 0.f);
      O[(size_t)(c0 + 2) * 4096 + n] = fmaxf(g * acc[i][j].z + R[(size_t)(c0 + 2) * 4096 + n], 0.f);
      O[(size_t)(c0 + 3) * 4096 + n] = fmaxf(g * acc[i][j].w + R[(size_t)(c0 + 3) * 4096 + n], 0.f);
    }
  }
}

// ---------------------------------------------------------------------------
extern "C" void kernel_launch(void* const* d_in, const int* in_sizes, int n_in,
                              void* d_out, int out_size, void* d_ws, size_t ws_size,
                              hipStream_t stream) {
  char* ws = (char*)d_ws;
  unsigned short* wb  = (unsigned short*)(ws);              //  6 x 512x512 bf16
  unsigned short* xt  = (unsigned short*)(ws + 3145728);    //  4 x [2][4096][512]
  unsigned short* qkv = (unsigned short*)(ws + 36700160);   // 12 x [4096x512]
  unsigned short* tt  = (unsigned short*)(ws + 87031808);   //  4 x [4096x4096]
  float* pz  = (float*)(ws + 3145728);                      // overlaps dead xt
  float* cb  = (float*)(ws + 3145728 + 2097152);

  // 1. weights -> bf16
  WArgs wa;
  for (int i = 0; i < 6; ++i) {
    wa.src[i] = (const float*)d_in[4 + 2 * i];
    wa.dst[i] = wb + (size_t)i * 262144;
  }
  k_cvtw<<<dim3(128, 6), 256, 0, stream>>>(wa);

  // 2. feature maps -> transposed bf16 Xt[b][n][c]
  TArgs ta;
  for (int ai = 0; ai < 4; ++ai) {
    ta.src[ai] = (const float*)d_in[ai];
    ta.dst[ai] = xt + (size_t)ai * 4194304;
  }
  k_tcvt<<<dim3(64, 16, 8), 256, 0, stream>>>(ta);

  // 3. six convs x two batches (q_rd, k_rd, v_rd, q_dr, k_dr, v_dr)
  const int srcArr[6] = {2, 0, 3, 3, 1, 1};
  const int trans[6] = {1, 1, 0, 1, 1, 0};
  ConvArgs ca;
  for (int ci = 0; ci < 6; ++ci)
    for (int b = 0; b < 2; ++b) {
      int zz = ci * 2 + b;
      ca.W[zz] = wb + (size_t)ci * 262144;
      ca.X[zz] = xt + (size_t)srcArr[ci] * 4194304 + (size_t)b * 2097152;
      ca.bias[zz] = (const float*)d_in[5 + 2 * ci];
      ca.out[zz] = qkv + (size_t)zz * 2097152;
      ca.trans[zz] = trans[ci];
    }
  k_conv<<<dim3(32, 4, 12), 256, 0, stream>>>(ca);

  // 4. Et[n][m] = exp(Qt Kt^T) + fused partial sums (256^2 tile, 8 waves)
  QKArgs qa;
  for (int path = 0; path < 2; ++path)
    for (int b = 0; b < 2; ++b) {
      int zz = path * 2 + b;
      qa.Q[zz] = qkv + (size_t)((path * 3 + 0) * 2 + b) * 2097152;  // Qt (rows=n)
      qa.K[zz] = qkv + (size_t)((path * 3 + 1) * 2 + b) * 2097152;  // Kt (cols=m)
      qa.T[zz] = tt + (size_t)zz * 16777216;
    }
  qa.pz = pz;
  k_qk<<<dim3(16, 16, 4), 512, 0, stream>>>(qa);

  // 5. merge partials -> c[m] = 1/S
  k_stats2<<<dim3(16, 4), 256, 0, stream>>>(pz, cb);

  // 6. V' = V * c[m]
  VSArgs va;
  for (int path = 0; path < 2; ++path)
    for (int b = 0; b < 2; ++b)
      va.V[path * 2 + b] = qkv + (size_t)((path * 3 + 2) * 2 + b) * 2097152;
  va.c = cb;
  k_vscale<<<dim3(1024, 4), 256, 0, stream>>>(va);

  // 7. O = V' E + fused epilogue (Tc=256 x Tn=128, BK=64, TRIPLE-BUF,
  //    full fill, XCD-pinned V')
  PVArgs pa;
  const float* resid_src[2] = {(const float*)d_in[2], (const float*)d_in[3]};
  const float* gsrc[2] = {(const float*)d_in[16], (const float*)d_in[17]};
  for (int path = 0; path < 2; ++path)
    for (int b = 0; b < 2; ++b) {
      int zz = path * 2 + b;
      pa.V[zz] = qkv + (size_t)((path * 3 + 2) * 2 + b) * 2097152;
      pa.P[zz] = tt + (size_t)zz * 16777216;
      pa.resid[zz] = resid_src[path] + (size_t)b * 2097152;
      pa.gamma[zz] = gsrc[path];
      pa.out[zz] = (float*)d_out + (size_t)zz * 2097152;
    }
  k_pv<<<dim3(256), 512, 0, stream>>>(pa);
}

// Round 9
// 360.471 us; speedup vs baseline: 1.1602x; 1.0257x over previous
//
#include <hip/hip_runtime.h>
#include <stdint.h>

// ---------------------------------------------------------------------------
// FeatureMapTransformer: dual cross-attention (rd / dr paths), B=2, C=512,
// H=W=64 -> N=M=4096.
//   Qt[n][c], Kt[m][c] (transposed conv outs), V[c][m]        (bf16)
//   Et[n][m] = bf16(exp(sum_c Kt[m][c] Qt[n][c]))             (k_qk)
//   partial S[m] = sum_n exp(T) fused into k_qk -> c[m] = 1/S (k_stats2)
//   V'[c][m] = V[c][m] * c[m]                                 (k_vscale)
//   O[c][n]  = sum_m V'[c][m] E[n][m]  (split-K bf16 GEMM)    (k_pv)
//   out = relu(gamma*(P0+P1) + resid)                         (k_red)
// k_pv HISTORY: invariant 106-116 us across traffic volume (r7), tile
// aspect (r4), blocks/CU (r3), schedule (r5), lookahead depth (r8).
// Cycle accounting r7: 3580 cyc/iter = LDS 2070 (frag reads 128 KB + DMA
// 48 KB @85B/cyc) vs MFMA 1240 -> LDS-BOUND at 512 B/MFMA (64x64 wave
// tile). m201's verified 62% template uses 128x64 wave tiles (384 B/MFMA,
// MFMA > LDS). Full fill with 512-thr/128x64-wave blocks on a 512-row
// output requires SPLIT-K: 256^2 tile x K-half 2048, grid 2kh x 2cb x
// 16nb x 4z = 256 blocks. 4-phase/tile m201 schedule: {ds_read 4-8;
// 2 DMA; barrier; setprio 16 MFMA; barrier}, vmcnt(6) once per tile
// (tail: vmcnt(0) at t>=30). Staging rotates into just-freed regions:
// p0: A-k1(t+1)->nxt, p1: B-k0(t+2)->cur, p2: A-k0(t+2), p3: B-k1(t+2).
// Partials bf16 (error ~1e-4 after gamma~0.1 scaling) into dead Q/K qkv
// slots 0-3 / 6-9 (exactly 2 x 16.78 MB). k_red: 100 MB, fused epilogue.
// XCD = x&7 = kh+2z: per-XCD V' slice 2 MB = L2-resident.
// ---------------------------------------------------------------------------

typedef __attribute__((ext_vector_type(8))) __bf16 bf16x8;
typedef __attribute__((ext_vector_type(4))) float f32x4;

__device__ __forceinline__ unsigned short f2bf(float f) {
  union { float f; unsigned u; } v; v.f = f;
  unsigned r = v.u + 0x7FFFu + ((v.u >> 16) & 1u);
  return (unsigned short)(r >> 16);
}
__device__ __forceinline__ float bf2f(unsigned short b) {
  union { unsigned u; float f; } v; v.u = ((unsigned)b) << 16;
  return v.f;
}

__device__ __forceinline__ void async_copy16(const unsigned short* g,
                                             unsigned short* l) {
  __builtin_amdgcn_global_load_lds(
      (const __attribute__((address_space(1))) unsigned int*)g,
      (__attribute__((address_space(3))) unsigned int*)l, 16, 0, 0);
}

// Counted VMEM wait (literal immediates only). Memory clobber pins all
// memory ops (ds_read / global_load_lds) on the correct side.
template <int N>
__device__ __forceinline__ void waitcnt_vm() {
  if constexpr (N == 0) asm volatile("s_waitcnt vmcnt(0)" ::: "memory");
  else if constexpr (N == 4) asm volatile("s_waitcnt vmcnt(4)" ::: "memory");
  else if constexpr (N == 6) asm volatile("s_waitcnt vmcnt(6)" ::: "memory");
  else asm volatile("s_waitcnt vmcnt(8)" ::: "memory");
}

// C[128x128 at (rowbase,colbase)] += A[row][k] * B[col][k]^T, K-contig A/B.
// lds layout: [2 buffers][A|B][NSUB][128x32 sub-tile = 4096 shorts].
// 16B chunk c of row r lives at slot c^((r>>1)&3) (pre-swizzled on the
// global source side; global_load_lds dest stays linear).
template <int NSUB>
__device__ __forceinline__ void gemm_core(
    const unsigned short* __restrict__ Ag, const unsigned short* __restrict__ Bg,
    int K, int lda, int ldb, int rowbase, int colbase,
    f32x4 (&acc)[4][4], unsigned short* lds) {
  const int tid = threadIdx.x;
  const int w = tid >> 6, lane = tid & 63;
  const int quad = lane >> 4, l16 = lane & 15;
  const int wm = (w >> 1) << 6, wn = (w & 1) << 6;
  const int rbase = (w << 5) + (lane >> 2);
  const int BK = 32 * NSUB;

  auto stage = [&](int k0, unsigned short* buf) {
#pragma unroll
    for (int half = 0; half < NSUB; ++half) {
      int kh = k0 + (half << 5);
      unsigned short* Ah = buf + (half << 12);
      unsigned short* Bh = buf + (NSUB << 12) + (half << 12);
#pragma unroll
      for (int i = 0; i < 2; ++i) {
        int rloc = rbase + (i << 4);
        int cg = (lane & 3) ^ ((rloc >> 1) & 3);
        int koff = kh + (cg << 3);
        int ldsoff = ((w << 5) + (i << 4)) << 5;
        async_copy16(Ag + (size_t)(rowbase + rloc) * lda + koff, Ah + ldsoff);
        async_copy16(Bg + (size_t)(colbase + rloc) * ldb + koff, Bh + ldsoff);
      }
    }
  };

  auto compute = [&](const unsigned short* buf) {
#pragma unroll
    for (int half = 0; half < NSUB; ++half) {
      const unsigned short* Ah = buf + (half << 12);
      const unsigned short* Bh = buf + (NSUB << 12) + (half << 12);
      bf16x8 af[4], bfr[4];
#pragma unroll
      for (int i = 0; i < 4; ++i) {
        int r = wm + (i << 4) + l16;
        af[i] = *(const bf16x8*)(Ah + (r << 5) + ((quad ^ ((r >> 1) & 3)) << 3));
      }
#pragma unroll
      for (int j = 0; j < 4; ++j) {
        int r = wn + (j << 4) + l16;
        bfr[j] = *(const bf16x8*)(Bh + (r << 5) + ((quad ^ ((r >> 1) & 3)) << 3));
      }
#pragma unroll
      for (int i = 0; i < 4; ++i)
#pragma unroll
        for (int j = 0; j < 4; ++j)
          acc[i][j] = __builtin_amdgcn_mfma_f32_16x16x32_bf16(af[i], bfr[j], acc[i][j], 0, 0, 0);
    }
  };

  unsigned short* b0 = lds;                   // current compute buffer
  unsigned short* b1 = lds + (NSUB << 13);    // in-flight prefetch buffer
  const int nt = K / BK;

  stage(0, b0);
  stage(BK, b1);
  for (int t = 0; t < nt - 1; ++t) {
    waitcnt_vm<4 * NSUB>();          // own stage(t) retired; stage(t+1) rides
    __builtin_amdgcn_s_barrier();    // => all waves' stage(t) complete
    compute(b0);
    __builtin_amdgcn_sched_barrier(0);
    __builtin_amdgcn_s_barrier();    // all waves done reading b0
    if (t + 2 < nt) stage((t + 2) * BK, b0);
    unsigned short* tmp = b0; b0 = b1; b1 = tmp;
  }
  waitcnt_vm<0>();                   // final tile: drain
  __builtin_amdgcn_s_barrier();
  compute(b0);
  __syncthreads();                   // LDS safe for caller epilogue reuse
}

// ---------------- weight fp32 -> bf16 (vectorized) -----------------------
struct WArgs { const float* src[6]; unsigned short* dst[6]; };
__global__ __launch_bounds__(256) void k_cvtw(WArgs a) {
  int z = blockIdx.y;
  int i = (blockIdx.x * 256 + threadIdx.x) << 3;
  const float* s = a.src[z] + i;
  float4 v0 = *(const float4*)s;
  float4 v1 = *(const float4*)(s + 4);
  unsigned short pk[8] = {f2bf(v0.x), f2bf(v0.y), f2bf(v0.z), f2bf(v0.w),
                          f2bf(v1.x), f2bf(v1.y), f2bf(v1.z), f2bf(v1.w)};
  *(int4*)(a.dst[z] + i) = *(int4*)pk;
}

// ---------------- transpose+convert: x[b][c][n] f32 -> Xt[b][n][c] bf16 --
struct TArgs { const float* src[4]; unsigned short* dst[4]; };
__global__ __launch_bounds__(256) void k_tcvt(TArgs a) {
  __shared__ float tile[32][68];
  int z = blockIdx.z;  // array*2 + b
  const float* src = a.src[z >> 1] + (size_t)(z & 1) * (512 * 4096);
  unsigned short* dst = a.dst[z >> 1] + (size_t)(z & 1) * (4096 * 512);
  int n0 = blockIdx.x << 6;  // 64 n
  int c0 = blockIdx.y << 5;  // 32 c
  int tid = threadIdx.x;
  int q = tid & 15, r0 = tid >> 4;  // 16 lanes/row, 16 c-rows/pass
#pragma unroll
  for (int pass = 0; pass < 2; ++pass) {
    int r = r0 + (pass << 4);
    *(float4*)&tile[r][q << 2] =
        *(const float4*)(src + (size_t)(c0 + r) * 4096 + n0 + (q << 2));
  }
  __syncthreads();
  int j = tid >> 2, c8 = (tid & 3) << 3;  // n row j, 8 c's per thread
  unsigned short pk[8];
#pragma unroll
  for (int k = 0; k < 8; ++k) pk[k] = f2bf(tile[c8 + k][j]);
  *(int4*)(dst + (size_t)(n0 + j) * 512 + c0 + c8) = *(int4*)pk;
}

// ---------------- conv1x1 GEMMs: Y = W X^T + bias ------------------------
struct ConvArgs {
  const unsigned short* W[12];
  const unsigned short* X[12];
  const float* bias[12];
  unsigned short* out[12];
  int trans[12];
};
__global__ __launch_bounds__(256) void k_conv(ConvArgs a) {
  __shared__ unsigned short sh[16384];  // 2 buf x (A 4K + B 4K shorts) = 32 KB
  int z = blockIdx.z;
  int trans = a.trans[z];
  int rowbase = (trans ? blockIdx.x : blockIdx.y) << 7;
  int colbase = (trans ? blockIdx.y : blockIdx.x) << 7;
  const unsigned short* Ag = trans ? a.X[z] : a.W[z];
  const unsigned short* Bg = trans ? a.W[z] : a.X[z];
  f32x4 acc[4][4];
#pragma unroll
  for (int i = 0; i < 4; ++i)
#pragma unroll
    for (int j = 0; j < 4; ++j) acc[i][j] = (f32x4){0.f, 0.f, 0.f, 0.f};
  gemm_core<1>(Ag, Bg, 512, 512, 512, rowbase, colbase, acc, sh);

  const int tid = threadIdx.x, w = tid >> 6, lane = tid & 63;
  const int quad = lane >> 4, l16 = lane & 15;
  const int wm = (w >> 1) << 6, wn = (w & 1) << 6;
  const float* bias = a.bias[z];
  unsigned short* out = a.out[z];
  if (trans) {
    float bo[4];
#pragma unroll
    for (int j = 0; j < 4; ++j) bo[j] = bias[colbase + wn + (j << 4) + l16];
#pragma unroll
    for (int i = 0; i < 4; ++i) {
      int n0 = rowbase + wm + (i << 4) + (quad << 2);
#pragma unroll
      for (int j = 0; j < 4; ++j) {
        int o = colbase + wn + (j << 4) + l16;
        out[(size_t)(n0 + 0) * 512 + o] = f2bf(acc[i][j].x + bo[j]);
        out[(size_t)(n0 + 1) * 512 + o] = f2bf(acc[i][j].y + bo[j]);
        out[(size_t)(n0 + 2) * 512 + o] = f2bf(acc[i][j].z + bo[j]);
        out[(size_t)(n0 + 3) * 512 + o] = f2bf(acc[i][j].w + bo[j]);
      }
    }
  } else {
#pragma unroll
    for (int i = 0; i < 4; ++i) {
      int o0 = rowbase + wm + (i << 4) + (quad << 2);
      float b0 = bias[o0], b1 = bias[o0 + 1], b2 = bias[o0 + 2], b3 = bias[o0 + 3];
#pragma unroll
      for (int j = 0; j < 4; ++j) {
        int n = colbase + wn + (j << 4) + l16;
        out[(size_t)(o0 + 0) * 4096 + n] = f2bf(acc[i][j].x + b0);
        out[(size_t)(o0 + 1) * 4096 + n] = f2bf(acc[i][j].y + b1);
        out[(size_t)(o0 + 2) * 4096 + n] = f2bf(acc[i][j].z + b2);
        out[(size_t)(o0 + 3) * 4096 + n] = f2bf(acc[i][j].w + b3);
      }
    }
  }
}

// ---------------- Et[n][m] = exp(Qt Kt^T), fused partial sum S[m] --------
// OPERAND-SWAPPED: A=Qt (rows=n), B=Kt (cols=m) -> m is the lane dim.
// 256x256 tile, 8 waves (wave grid 2r x 4c, wave tile 128x64), BK=32.
struct QKArgs {
  const unsigned short* Q[4]; const unsigned short* K[4]; unsigned short* T[4];
  float* pz;  // [4 z][16 nblk][4096 m] partial sums
};
__global__ __launch_bounds__(512) void k_qk(QKArgs a) {
  __shared__ unsigned short sh[32768];  // 64 KB
  int z = blockIdx.z;
  int nbase = blockIdx.y << 8;  // 256 rows = n
  int mbase = blockIdx.x << 8;  // 256 cols = m
  const unsigned short* Ag = a.Q[z];
  const unsigned short* Bg = a.K[z];

  const int tid = threadIdx.x;
  const int w = tid >> 6, lane = tid & 63;
  const int quad = lane >> 4, l16 = lane & 15;
  const int wr = w >> 2, wc = w & 3;
  const int wm = wr << 7;       // wave A-row base (0/128)
  const int wn = wc << 6;       // wave B-row base (0/64/128/192)
  const int rbase = (w << 5) + (lane >> 2);

  f32x4 acc[8][4];
#pragma unroll
  for (int i = 0; i < 8; ++i)
#pragma unroll
    for (int j = 0; j < 4; ++j) acc[i][j] = (f32x4){0.f, 0.f, 0.f, 0.f};

  auto stage = [&](int k0, unsigned short* buf) {
    unsigned short* Ah = buf;
    unsigned short* Bh = buf + 8192;
#pragma unroll
    for (int i = 0; i < 2; ++i) {
      int rloc = rbase + (i << 4);
      int cg = (lane & 3) ^ ((rloc >> 1) & 3);
      int koff = k0 + (cg << 3);
      int ldsoff = ((w << 5) + (i << 4)) << 5;
      async_copy16(Ag + (size_t)(nbase + rloc) * 512 + koff, Ah + ldsoff);
      async_copy16(Bg + (size_t)(mbase + rloc) * 512 + koff, Bh + ldsoff);
    }
  };

  auto compute = [&](const unsigned short* buf) {
    const unsigned short* Ah = buf;
    const unsigned short* Bh = buf + 8192;
    bf16x8 af[8], bfr[4];
#pragma unroll
    for (int i = 0; i < 8; ++i) {
      int r = wm + (i << 4) + l16;
      af[i] = *(const bf16x8*)(Ah + (r << 5) + ((quad ^ ((r >> 1) & 3)) << 3));
    }
#pragma unroll
    for (int j = 0; j < 4; ++j) {
      int r = wn + (j << 4) + l16;
      bfr[j] = *(const bf16x8*)(Bh + (r << 5) + ((quad ^ ((r >> 1) & 3)) << 3));
    }
#pragma unroll
    for (int i = 0; i < 8; ++i)
#pragma unroll
      for (int j = 0; j < 4; ++j)
        acc[i][j] = __builtin_amdgcn_mfma_f32_16x16x32_bf16(af[i], bfr[j], acc[i][j], 0, 0, 0);
  };

  unsigned short* b0 = sh;
  unsigned short* b1 = sh + 16384;
  stage(0, b0);
  stage(32, b1);
  for (int t = 0; t < 15; ++t) {
    waitcnt_vm<4>();
    __builtin_amdgcn_s_barrier();
    compute(b0);
    __builtin_amdgcn_sched_barrier(0);
    __builtin_amdgcn_s_barrier();
    if (t + 2 < 16) stage((t + 2) << 5, b0);
    unsigned short* tmp = b0; b0 = b1; b1 = tmp;
  }
  waitcnt_vm<0>();
  __builtin_amdgcn_s_barrier();
  compute(b0);
  __syncthreads();

  unsigned short* T = a.T[z];
  float sjv[4] = {0.f, 0.f, 0.f, 0.f};
#pragma unroll
  for (int i = 0; i < 8; ++i) {
    int n0 = nbase + wm + (i << 4) + (quad << 2);
#pragma unroll
    for (int j = 0; j < 4; ++j) {
      int m = mbase + wn + (j << 4) + l16;
      float e0 = __expf(acc[i][j].x);
      float e1 = __expf(acc[i][j].y);
      float e2 = __expf(acc[i][j].z);
      float e3 = __expf(acc[i][j].w);
      T[(size_t)(n0 + 0) * 4096 + m] = f2bf(e0);
      T[(size_t)(n0 + 1) * 4096 + m] = f2bf(e1);
      T[(size_t)(n0 + 2) * 4096 + m] = f2bf(e2);
      T[(size_t)(n0 + 3) * 4096 + m] = f2bf(e3);
      sjv[j] += e0 + e1 + e2 + e3;
    }
  }
  float* red = (float*)sh;  // [8 waves][64 m-local]
#pragma unroll
  for (int j = 0; j < 4; ++j) {
    float s = sjv[j];
    s += __shfl_xor(s, 16, 64);
    s += __shfl_xor(s, 32, 64);
    if (quad == 0) red[(w << 6) + (j << 4) + l16] = s;
  }
  __syncthreads();
  if (tid < 256) {
    float S = red[tid] + red[tid + 256];
    a.pz[((z << 4) + blockIdx.y) * 4096 + mbase + tid] = S;
  }
}

// ---------------- merge 16 partials -> c[m] = 1/S ------------------------
__global__ __launch_bounds__(256) void k_stats2(const float* __restrict__ pz,
                                                float* __restrict__ c) {
  int m = (blockIdx.x << 8) + threadIdx.x;
  int z = blockIdx.y;
  float S = 0.f;
#pragma unroll
  for (int k = 0; k < 16; ++k) S += pz[((z << 4) + k) * 4096 + m];
  c[z * 4096 + m] = 1.f / S;
}

// ---------------- V'[c][m] = V[c][m] * c[m] (in place) -------------------
struct VSArgs { unsigned short* V[4]; const float* c; };
__global__ __launch_bounds__(256) void k_vscale(VSArgs a) {
  int z = blockIdx.y;
  int t = blockIdx.x * 256 + threadIdx.x;
  int m0 = (t & 511) << 3;
  int row = t >> 9;
  unsigned short* p = a.V[z] + (size_t)row * 4096 + m0;
  const float* cz = a.c + z * 4096 + m0;
  int4 raw = *(const int4*)p;
  unsigned short* u = (unsigned short*)&raw;
#pragma unroll
  for (int j = 0; j < 8; ++j) u[j] = f2bf(bf2f(u[j]) * cz[j]);
  *(int4*)p = raw;
}

// ---------------- k_pv: P[kh] = V'[:, khalf] E[:, khalf]^T (split-K) -----
// 256x256 tile, 8 waves (2c x 4n), wave tile 128x64, acc[8][4], BK=64 in
// 2 ksubs of 32. K-half = 2048 -> 32 tiles. LDS 128 KB: per buffer (32768
// shorts): A-k0 [0,8K), A-k1 [8K,16K), B-k0 [16K,24K), B-k1 [24K,32K).
// 4 phases/tile: p0 {B-k0(4)+A-k0.lo(4) reads; stage A-k1(t+1)->nxt},
// p1 {A-k0.hi(4); stage B-k0(t+2)->cur}, p2 {B-k1+A-k1.lo(8); stage
// A-k0(t+2)}, p3 {A-k1.hi(4); stage B-k1(t+2); vmcnt(6)}. Each phase:
// reads; stage; barrier; setprio 16 MFMA; barrier. vmcnt never 0 until
// t>=30. Region safety: each stage targets the region freed by the
// previous phase's closing barrier. Partial out: bf16 [z][c][n].
struct PVArgs {
  const unsigned short* V[4];
  const unsigned short* P[4];  // Et[n][m]
  unsigned short* PP[2];       // partials per k-half
};
__global__ __launch_bounds__(512) void k_pv(PVArgs a) {
  __shared__ unsigned short sh[65536];  // 128 KB
  int x = blockIdx.x;            // x = kh + 2z + 8t -> XCD = x&7 = kh+2z
  int kh = x & 1;
  int z  = (x >> 1) & 3;
  int tt = x >> 3;               // 0..31
  int cb = tt & 1;
  int nb = tt >> 1;              // 0..15
  int cbase = cb << 8;
  int nbase = nb << 8;
  int khb = kh << 11;            // k-half base: 0 / 2048
  const unsigned short* Ag = a.V[z];   // V'[c][m], stride 4096
  const unsigned short* Bg = a.P[z];   // E[n][m],  stride 4096

  const int tid = threadIdx.x;
  const int w = tid >> 6, lane = tid & 63;
  const int quad = lane >> 4, l16 = lane & 15;
  const int wm = (w >> 2) << 7;   // c offset 0/128
  const int wn = (w & 3) << 6;    // n offset 0/64/128/192

  f32x4 acc[8][4];
#pragma unroll
  for (int i = 0; i < 8; ++i)
#pragma unroll
    for (int j = 0; j < 4; ++j) acc[i][j] = (f32x4){0.f, 0.f, 0.f, 0.f};

  // stage one 256x32 ksub (16 KB = 2 loads/thread). Linear dest: thread
  // writes shorts [tid*8 + r*4096); row=(tid>>2)+(r<<7), slot=tid&3;
  // content chunk cg = slot ^ ((row>>1)&3) (pre-swizzled source).
  auto stageA = [&](int kg, int ksub, unsigned short* buf) {
#pragma unroll
    for (int r = 0; r < 2; ++r) {
      int row = (tid >> 2) + (r << 7);
      int cg = (tid & 3) ^ ((row >> 1) & 3);
      async_copy16(Ag + (size_t)(cbase + row) * 4096 + kg + (ksub << 5) + (cg << 3),
                   buf + (ksub << 13) + (r << 12) + (w << 9));
    }
  };
  auto stageB = [&](int kg, int ksub, unsigned short* buf) {
#pragma unroll
    for (int r = 0; r < 2; ++r) {
      int row = (tid >> 2) + (r << 7);
      int cg = (tid & 3) ^ ((row >> 1) & 3);
      async_copy16(Bg + (size_t)(nbase + row) * 4096 + kg + (ksub << 5) + (cg << 3),
                   buf + 16384 + (ksub << 13) + (r << 12) + (w << 9));
    }
  };

  bf16x8 afv[4], bfv[4];
  auto rdA = [&](const unsigned short* buf, int ksub, int half) {
    const unsigned short* As = buf + (ksub << 13);
#pragma unroll
    for (int i = 0; i < 4; ++i) {
      int r = wm + (half << 6) + (i << 4) + l16;
      afv[i] = *(const bf16x8*)(As + (r << 5) + ((quad ^ ((r >> 1) & 3)) << 3));
    }
  };
  auto rdB = [&](const unsigned short* buf, int ksub) {
    const unsigned short* Bs = buf + 16384 + (ksub << 13);
#pragma unroll
    for (int j = 0; j < 4; ++j) {
      int r = wn + (j << 4) + l16;
      bfv[j] = *(const bf16x8*)(Bs + (r << 5) + ((quad ^ ((r >> 1) & 3)) << 3));
    }
  };
  auto mfmaQ = [&](int ib) {
#pragma unroll
    for (int i = 0; i < 4; ++i)
#pragma unroll
      for (int j = 0; j < 4; ++j)
        acc[ib + i][j] = __builtin_amdgcn_mfma_f32_16x16x32_bf16(afv[i], bfv[j], acc[ib + i][j], 0, 0, 0);
  };

  unsigned short* b0 = sh;
  unsigned short* b1 = sh + 32768;

  // prologue: tile0 full (8 loads) then tile1 minus A-k1 (6 loads).
  stageA(khb, 0, b0); stageA(khb, 1, b0); stageB(khb, 0, b0); stageB(khb, 1, b0);
  stageB(khb + 64, 0, b1); stageA(khb + 64, 0, b1); stageB(khb + 64, 1, b1);
  waitcnt_vm<6>();                 // tile0's 8 retired; tile1's 6 ride
  __builtin_amdgcn_s_barrier();

  for (int t = 0; t < 32; ++t) {
    unsigned short* cur = (t & 1) ? b1 : b0;
    unsigned short* nxt = (t & 1) ? b0 : b1;
    int kgc = khb + ((t + 2) << 6);
    // phase 0: B-k0 + A-k0.lo reads; stage A-k1(t+1) (nxt.A-k1 freed t-1 p3)
    rdB(cur, 0);
    rdA(cur, 0, 0);
    if (t + 1 < 32) stageA(khb + ((t + 1) << 6), 1, nxt);
    __builtin_amdgcn_s_barrier();
    __builtin_amdgcn_s_setprio(1); mfmaQ(0); __builtin_amdgcn_s_setprio(0);
    __builtin_amdgcn_s_barrier();
    // phase 1: A-k0.hi; stage B-k0(t+2) (cur.B-k0 freed at p0 barrier)
    rdA(cur, 0, 1);
    if (t + 2 < 32) stageB(kgc, 0, cur);
    __builtin_amdgcn_s_barrier();
    __builtin_amdgcn_s_setprio(1); mfmaQ(4); __builtin_amdgcn_s_setprio(0);
    __builtin_amdgcn_s_barrier();
    // phase 2: B-k1 + A-k1.lo; stage A-k0(t+2) (cur.A-k0 freed at p1)
    rdB(cur, 1);
    rdA(cur, 1, 0);
    if (t + 2 < 32) stageA(kgc, 0, cur);
    __builtin_amdgcn_s_barrier();
    __builtin_amdgcn_s_setprio(1); mfmaQ(0); __builtin_amdgcn_s_setprio(0);
    __builtin_amdgcn_s_barrier();
    // phase 3: A-k1.hi; stage B-k1(t+2) (cur.B-k1 freed at p2); tile wait
    rdA(cur, 1, 1);
    if (t + 2 < 32) stageB(kgc, 1, cur);
    __builtin_amdgcn_s_barrier();
    __builtin_amdgcn_s_setprio(1); mfmaQ(4); __builtin_amdgcn_s_setprio(0);
    if (t < 30) waitcnt_vm<6>(); else waitcnt_vm<0>();
    __builtin_amdgcn_s_barrier();
  }

  // partial store: PP[kh][z][c][n] bf16
  unsigned short* PP = a.PP[kh] + (size_t)z * 2097152;
#pragma unroll
  for (int i = 0; i < 8; ++i) {
    int c0 = cbase + wm + ((i >> 2) << 6) + ((i & 3) << 4) + (quad << 2);
#pragma unroll
    for (int j = 0; j < 4; ++j) {
      int n = nbase + wn + (j << 4) + l16;
      PP[(size_t)(c0 + 0) * 4096 + n] = f2bf(acc[i][j].x);
      PP[(size_t)(c0 + 1) * 4096 + n] = f2bf(acc[i][j].y);
      PP[(size_t)(c0 + 2) * 4096 + n] = f2bf(acc[i][j].z);
      PP[(size_t)(c0 + 3) * 4096 + n] = f2bf(acc[i][j].w);
    }
  }
}

// ---------------- k_red: out = relu(gamma*(P0+P1) + resid) ---------------
struct RArgs {
  const unsigned short* PP[2];
  const float* resid[4];
  const float* gamma[4];
  float* out[4];
};
__global__ __launch_bounds__(256) void k_red(RArgs a) {
  int z = blockIdx.y;
  size_t i = (((size_t)blockIdx.x << 8) + threadIdx.x) << 3;
  int4 q0 = *(const int4*)(a.PP[0] + (size_t)z * 2097152 + i);
  int4 q1 = *(const int4*)(a.PP[1] + (size_t)z * 2097152 + i);
  const unsigned short* u0 = (const unsigned short*)&q0;
  const unsigned short* u1 = (const unsigned short*)&q1;
  float g = a.gamma[z][0];
  const float* R = a.resid[z] + i;
  float4 r0 = *(const float4*)R;
  float4 r1 = *(const float4*)(R + 4);
  const float* rv = (const float*)&r0;
  const float* rw = (const float*)&r1;
  float res[8];
#pragma unroll
  for (int k = 0; k < 4; ++k)
    res[k] = fmaxf(g * (bf2f(u0[k]) + bf2f(u1[k])) + rv[k], 0.f);
#pragma unroll
  for (int k = 4; k < 8; ++k)
    res[k] = fmaxf(g * (bf2f(u0[k]) + bf2f(u1[k])) + rw[k - 4], 0.f);
  float* O = a.out[z] + i;
  *(float4*)O = *(float4*)res;
  *(float4*)(O + 4) = *(float4*)(res + 4);
}

// ---------------------------------------------------------------------------
extern "C" void kernel_launch(void* const* d_in, const int* in_sizes, int n_in,
                              void* d_out, int out_size, void* d_ws, size_t ws_size,
                              hipStream_t stream) {
  char* ws = (char*)d_ws;
  unsigned short* wb  = (unsigned short*)(ws);              //  6 x 512x512 bf16
  unsigned short* xt  = (unsigned short*)(ws + 3145728);    //  4 x [2][4096][512]
  unsigned short* qkv = (unsigned short*)(ws + 36700160);   // 12 x [4096x512]
  unsigned short* tt  = (unsigned short*)(ws + 87031808);   //  4 x [4096x4096]
  float* pz  = (float*)(ws + 3145728);                      // overlaps dead xt
  float* cb  = (float*)(ws + 3145728 + 2097152);
  // split-K partials reuse dead Q/K conv outputs (each exactly 16777216 B):
  unsigned short* pp0 = qkv;                          // slots 0-3 (Q_rd,K_rd)
  unsigned short* pp1 = qkv + (size_t)6 * 2097152;    // slots 6-9 (Q_dr,K_dr)

  // 1. weights -> bf16
  WArgs wa;
  for (int i = 0; i < 6; ++i) {
    wa.src[i] = (const float*)d_in[4 + 2 * i];
    wa.dst[i] = wb + (size_t)i * 262144;
  }
  k_cvtw<<<dim3(128, 6), 256, 0, stream>>>(wa);

  // 2. feature maps -> transposed bf16 Xt[b][n][c]
  TArgs ta;
  for (int ai = 0; ai < 4; ++ai) {
    ta.src[ai] = (const float*)d_in[ai];
    ta.dst[ai] = xt + (size_t)ai * 4194304;
  }
  k_tcvt<<<dim3(64, 16, 8), 256, 0, stream>>>(ta);

  // 3. six convs x two batches (q_rd, k_rd, v_rd, q_dr, k_dr, v_dr)
  const int srcArr[6] = {2, 0, 3, 3, 1, 1};
  const int trans[6] = {1, 1, 0, 1, 1, 0};
  ConvArgs ca;
  for (int ci = 0; ci < 6; ++ci)
    for (int b = 0; b < 2; ++b) {
      int zz = ci * 2 + b;
      ca.W[zz] = wb + (size_t)ci * 262144;
      ca.X[zz] = xt + (size_t)srcArr[ci] * 4194304 + (size_t)b * 2097152;
      ca.bias[zz] = (const float*)d_in[5 + 2 * ci];
      ca.out[zz] = qkv + (size_t)zz * 2097152;
      ca.trans[zz] = trans[ci];
    }
  k_conv<<<dim3(32, 4, 12), 256, 0, stream>>>(ca);

  // 4. Et[n][m] = exp(Qt Kt^T) + fused partial sums (256^2 tile, 8 waves)
  QKArgs qa;
  for (int path = 0; path < 2; ++path)
    for (int b = 0; b < 2; ++b) {
      int zz = path * 2 + b;
      qa.Q[zz] = qkv + (size_t)((path * 3 + 0) * 2 + b) * 2097152;  // Qt (rows=n)
      qa.K[zz] = qkv + (size_t)((path * 3 + 1) * 2 + b) * 2097152;  // Kt (cols=m)
      qa.T[zz] = tt + (size_t)zz * 16777216;
    }
  qa.pz = pz;
  k_qk<<<dim3(16, 16, 4), 512, 0, stream>>>(qa);

  // 5. merge partials -> c[m] = 1/S
  k_stats2<<<dim3(16, 4), 256, 0, stream>>>(pz, cb);

  // 6. V' = V * c[m]
  VSArgs va;
  for (int path = 0; path < 2; ++path)
    for (int b = 0; b < 2; ++b)
      va.V[path * 2 + b] = qkv + (size_t)((path * 3 + 2) * 2 + b) * 2097152;
  va.c = cb;
  k_vscale<<<dim3(1024, 4), 256, 0, stream>>>(va);

  // 7. split-K PV partials (256^2 tile, wave 128x64, 4-phase, full fill)
  PVArgs pa;
  for (int path = 0; path < 2; ++path)
    for (int b = 0; b < 2; ++b) {
      int zz = path * 2 + b;
      pa.V[zz] = qkv + (size_t)((path * 3 + 2) * 2 + b) * 2097152;
      pa.P[zz] = tt + (size_t)zz * 16777216;
    }
  pa.PP[0] = pp0;
  pa.PP[1] = pp1;
  k_pv<<<dim3(256), 512, 0, stream>>>(pa);

  // 8. reduce + fused epilogue
  RArgs ra;
  const float* resid_src[2] = {(const float*)d_in[2], (const float*)d_in[3]};
  const float* gsrc[2] = {(const float*)d_in[16], (const float*)d_in[17]};
  ra.PP[0] = pp0;
  ra.PP[1] = pp1;
  for (int path = 0; path < 2; ++path)
    for (int b = 0; b < 2; ++b) {
      int zz = path * 2 + b;
      ra.resid[zz] = resid_src[path] + (size_t)b * 2097152;
      ra.gamma[zz] = gsrc[path];
      ra.out[zz] = (float*)d_out + (size_t)zz * 2097152;
    }
  k_red<<<dim3(1024, 4), 256, 0, stream>>>(ra);
}

// Round 10
// 348.363 us; speedup vs baseline: 1.2006x; 1.0348x over previous
//
#include <hip/hip_runtime.h>
#include <stdint.h>

// ---------------------------------------------------------------------------
// FeatureMapTransformer: dual cross-attention (rd / dr paths), B=2, C=512,
// H=W=64 -> N=M=4096.
//   Qt[n][c], Kt[m][c] (transposed conv outs), V[c][m]        (bf16)
//   Et[n][m] = bf16(exp(sum_c Kt[m][c] Qt[n][c]))             (k_qk)
//   partial S[m] = sum_n exp(T) fused into k_qk -> c[m] = 1/S (k_stats2)
//   V'[c][m] = V[c][m] * c[m]                                 (k_vscale)
//   O[c][n]  = sum_m V'[c][m] E[n][m]  (split-K bf16 GEMM)    (k_pv)
//   out = relu(gamma*(P0+P1) + resid)                         (k_red)
// r9 RESULT: k_pv 115->~88 us (split-K 256^2, wave 128x64, 4-phase) --
// structure validated, 31% util. Top kernel now k_qk 99 us (28% util,
// coarse BK=32 loop), second target k_conv (~50-70 us, 128^2 tiles).
// Round-19: shared gemm256 core for k_qk AND k_conv -- 256^2 tile, 8
// waves, wave tile 128x64, acc[8][4], BK=32, 64 KB LDS (keeps 2 blocks/
// CU so block epilogues overlap neighbors' compute -- deliberate vs
// k_pv's 128 KB), 2 fine phases/tile mirroring r9's proven pattern:
//   p0 {rdB+rdA.lo ; stage A(t+1)->nxt ; bar ; setprio 16 MFMA ; bar}
//   p1 {rdA.hi     ; stage B(t+2)->cur ; bar ; setprio 16 MFMA ;
//       vmcnt(2) ; bar}
// (region freed by previous phase's closing barrier; vmcnt(2) = newest
// 2 loads ride; 0 only at t>=14 tail). k_conv: grid 16x2x12 = 384 blocks
// of 512 thr, X re-reads halve (16->8 MB/z). k_pv/k_red unchanged (r9).
// ---------------------------------------------------------------------------

typedef __attribute__((ext_vector_type(8))) __bf16 bf16x8;
typedef __attribute__((ext_vector_type(4))) float f32x4;

__device__ __forceinline__ unsigned short f2bf(float f) {
  union { float f; unsigned u; } v; v.f = f;
  unsigned r = v.u + 0x7FFFu + ((v.u >> 16) & 1u);
  return (unsigned short)(r >> 16);
}
__device__ __forceinline__ float bf2f(unsigned short b) {
  union { unsigned u; float f; } v; v.u = ((unsigned)b) << 16;
  return v.f;
}

__device__ __forceinline__ void async_copy16(const unsigned short* g,
                                             unsigned short* l) {
  __builtin_amdgcn_global_load_lds(
      (const __attribute__((address_space(1))) unsigned int*)g,
      (__attribute__((address_space(3))) unsigned int*)l, 16, 0, 0);
}

// Counted VMEM wait (literal immediates only). Memory clobber pins all
// memory ops (ds_read / global_load_lds) on the correct side.
template <int N>
__device__ __forceinline__ void waitcnt_vm() {
  if constexpr (N == 0) asm volatile("s_waitcnt vmcnt(0)" ::: "memory");
  else if constexpr (N == 2) asm volatile("s_waitcnt vmcnt(2)" ::: "memory");
  else if constexpr (N == 4) asm volatile("s_waitcnt vmcnt(4)" ::: "memory");
  else if constexpr (N == 6) asm volatile("s_waitcnt vmcnt(6)" ::: "memory");
  else asm volatile("s_waitcnt vmcnt(8)" ::: "memory");
}

// ---------------- shared 256^2 GEMM core (K=512, strides 512) ------------
// acc[8][4] += A[256 rows at rowbase][k] * B[256 rows at colbase][k]^T.
// 8 waves (2 row x 4 col), wave tile 128x64. BK=32, 16 tiles, 64 KB LDS:
// 2 buf x (A 256x32 [0,8192) + B 256x32 [8192,16384) shorts). 16B chunk
// slot = chunk ^ ((row>>1)&3), pre-swizzled on the global source side.
// 2 fine phases/tile with staggered staging (see header).
__device__ __forceinline__ void gemm256(
    const unsigned short* __restrict__ Ag, const unsigned short* __restrict__ Bg,
    int rowbase, int colbase, f32x4 (&acc)[8][4], unsigned short* sh) {
  const int tid = threadIdx.x;
  const int w = tid >> 6, lane = tid & 63;
  const int quad = lane >> 4, l16 = lane & 15;
  const int wm = (w >> 2) << 7;   // A-row offset 0/128
  const int wn = (w & 3) << 6;    // B-row offset 0/64/128/192
  const int srow = tid >> 2;                      // 0..127
  const int scg  = (tid & 3) ^ ((srow >> 1) & 3); // r-invariant (128%4==0)

  auto stageA = [&](int kg, unsigned short* buf) {
#pragma unroll
    for (int r = 0; r < 2; ++r) {
      int row = srow + (r << 7);
      async_copy16(Ag + (size_t)(rowbase + row) * 512 + kg + (scg << 3),
                   buf + (r << 12) + (w << 9));
    }
  };
  auto stageB = [&](int kg, unsigned short* buf) {
#pragma unroll
    for (int r = 0; r < 2; ++r) {
      int row = srow + (r << 7);
      async_copy16(Bg + (size_t)(colbase + row) * 512 + kg + (scg << 3),
                   buf + 8192 + (r << 12) + (w << 9));
    }
  };
  bf16x8 af[4], bfv[4];
  auto rdA = [&](const unsigned short* buf, int half) {
#pragma unroll
    for (int i = 0; i < 4; ++i) {
      int r = wm + (half << 6) + (i << 4) + l16;
      af[i] = *(const bf16x8*)(buf + (r << 5) + ((quad ^ ((r >> 1) & 3)) << 3));
    }
  };
  auto rdB = [&](const unsigned short* buf) {
#pragma unroll
    for (int j = 0; j < 4; ++j) {
      int r = wn + (j << 4) + l16;
      bfv[j] = *(const bf16x8*)(buf + 8192 + (r << 5) + ((quad ^ ((r >> 1) & 3)) << 3));
    }
  };
  auto mfmaQ = [&](int ib) {
#pragma unroll
    for (int i = 0; i < 4; ++i)
#pragma unroll
      for (int j = 0; j < 4; ++j)
        acc[ib + i][j] = __builtin_amdgcn_mfma_f32_16x16x32_bf16(af[i], bfv[j], acc[ib + i][j], 0, 0, 0);
  };

  unsigned short* b0 = sh;
  unsigned short* b1 = sh + 16384;

  // prologue: tile0 A+B, tile1 B (tile1 A staged in t=0 p0).
  stageA(0, b0); stageB(0, b0); stageB(32, b1);
  waitcnt_vm<2>();                 // tile0's 4 retired; B(t1) rides
  __builtin_amdgcn_s_barrier();

  for (int t = 0; t < 16; ++t) {
    unsigned short* cur = (t & 1) ? b1 : b0;
    unsigned short* nxt = (t & 1) ? b0 : b1;
    // phase 0: B + A.lo reads; stage A(t+1)->nxt (nxt.A freed t-1 p1)
    rdB(cur);
    rdA(cur, 0);
    if (t + 1 < 16) stageA((t + 1) << 5, nxt);
    __builtin_amdgcn_s_barrier();
    __builtin_amdgcn_s_setprio(1); mfmaQ(0); __builtin_amdgcn_s_setprio(0);
    __builtin_amdgcn_s_barrier();
    // phase 1: A.hi reads; stage B(t+2)->cur (cur.B freed at p0 barrier)
    rdA(cur, 1);
    if (t + 2 < 16) stageB((t + 2) << 5, cur);
    __builtin_amdgcn_s_barrier();
    __builtin_amdgcn_s_setprio(1); mfmaQ(4); __builtin_amdgcn_s_setprio(0);
    if (t < 14) waitcnt_vm<2>(); else waitcnt_vm<0>();  // tile t+1 landed
    __builtin_amdgcn_s_barrier();
  }
}

// ---------------- weight fp32 -> bf16 (vectorized) -----------------------
struct WArgs { const float* src[6]; unsigned short* dst[6]; };
__global__ __launch_bounds__(256) void k_cvtw(WArgs a) {
  int z = blockIdx.y;
  int i = (blockIdx.x * 256 + threadIdx.x) << 3;
  const float* s = a.src[z] + i;
  float4 v0 = *(const float4*)s;
  float4 v1 = *(const float4*)(s + 4);
  unsigned short pk[8] = {f2bf(v0.x), f2bf(v0.y), f2bf(v0.z), f2bf(v0.w),
                          f2bf(v1.x), f2bf(v1.y), f2bf(v1.z), f2bf(v1.w)};
  *(int4*)(a.dst[z] + i) = *(int4*)pk;
}

// ---------------- transpose+convert: x[b][c][n] f32 -> Xt[b][n][c] bf16 --
struct TArgs { const float* src[4]; unsigned short* dst[4]; };
__global__ __launch_bounds__(256) void k_tcvt(TArgs a) {
  __shared__ float tile[32][68];
  int z = blockIdx.z;  // array*2 + b
  const float* src = a.src[z >> 1] + (size_t)(z & 1) * (512 * 4096);
  unsigned short* dst = a.dst[z >> 1] + (size_t)(z & 1) * (4096 * 512);
  int n0 = blockIdx.x << 6;  // 64 n
  int c0 = blockIdx.y << 5;  // 32 c
  int tid = threadIdx.x;
  int q = tid & 15, r0 = tid >> 4;  // 16 lanes/row, 16 c-rows/pass
#pragma unroll
  for (int pass = 0; pass < 2; ++pass) {
    int r = r0 + (pass << 4);
    *(float4*)&tile[r][q << 2] =
        *(const float4*)(src + (size_t)(c0 + r) * 4096 + n0 + (q << 2));
  }
  __syncthreads();
  int j = tid >> 2, c8 = (tid & 3) << 3;  // n row j, 8 c's per thread
  unsigned short pk[8];
#pragma unroll
  for (int k = 0; k < 8; ++k) pk[k] = f2bf(tile[c8 + k][j]);
  *(int4*)(dst + (size_t)(n0 + j) * 512 + c0 + c8) = *(int4*)pk;
}

// ---------------- conv1x1 GEMMs: Y = W X^T + bias (256^2 core) -----------
// trans=1 (Q,K): rows=n (A=X), cols=o (B=W); out[n][o]. trans=0 (V):
// rows=o (A=W), cols=n (B=X); out[o][n]. Grid (16,2,12) x 512 thr.
struct ConvArgs {
  const unsigned short* W[12];
  const unsigned short* X[12];
  const float* bias[12];
  unsigned short* out[12];
  int trans[12];
};
__global__ __launch_bounds__(512) void k_conv(ConvArgs a) {
  __shared__ unsigned short sh[32768];  // 64 KB
  int z = blockIdx.z;
  int trans = a.trans[z];
  int rowbase = (trans ? blockIdx.x : blockIdx.y) << 8;
  int colbase = (trans ? blockIdx.y : blockIdx.x) << 8;
  const unsigned short* Ag = trans ? a.X[z] : a.W[z];
  const unsigned short* Bg = trans ? a.W[z] : a.X[z];
  f32x4 acc[8][4];
#pragma unroll
  for (int i = 0; i < 8; ++i)
#pragma unroll
    for (int j = 0; j < 4; ++j) acc[i][j] = (f32x4){0.f, 0.f, 0.f, 0.f};
  gemm256(Ag, Bg, rowbase, colbase, acc, sh);

  const int tid = threadIdx.x, w = tid >> 6, lane = tid & 63;
  const int quad = lane >> 4, l16 = lane & 15;
  const int wm = (w >> 2) << 7, wn = (w & 3) << 6;
  const float* bias = a.bias[z];
  unsigned short* out = a.out[z];
  if (trans) {
    float bo[4];
#pragma unroll
    for (int j = 0; j < 4; ++j) bo[j] = bias[colbase + wn + (j << 4) + l16];
#pragma unroll
    for (int i = 0; i < 8; ++i) {
      int n0 = rowbase + wm + ((i >> 2) << 6) + ((i & 3) << 4) + (quad << 2);
#pragma unroll
      for (int j = 0; j < 4; ++j) {
        int o = colbase + wn + (j << 4) + l16;
        out[(size_t)(n0 + 0) * 512 + o] = f2bf(acc[i][j].x + bo[j]);
        out[(size_t)(n0 + 1) * 512 + o] = f2bf(acc[i][j].y + bo[j]);
        out[(size_t)(n0 + 2) * 512 + o] = f2bf(acc[i][j].z + bo[j]);
        out[(size_t)(n0 + 3) * 512 + o] = f2bf(acc[i][j].w + bo[j]);
      }
    }
  } else {
#pragma unroll
    for (int i = 0; i < 8; ++i) {
      int o0 = rowbase + wm + ((i >> 2) << 6) + ((i & 3) << 4) + (quad << 2);
      float b0 = bias[o0], b1 = bias[o0 + 1], b2 = bias[o0 + 2], b3 = bias[o0 + 3];
#pragma unroll
      for (int j = 0; j < 4; ++j) {
        int n = colbase + wn + (j << 4) + l16;
        out[(size_t)(o0 + 0) * 4096 + n] = f2bf(acc[i][j].x + b0);
        out[(size_t)(o0 + 1) * 4096 + n] = f2bf(acc[i][j].y + b1);
        out[(size_t)(o0 + 2) * 4096 + n] = f2bf(acc[i][j].z + b2);
        out[(size_t)(o0 + 3) * 4096 + n] = f2bf(acc[i][j].w + b3);
      }
    }
  }
}

// ---------------- Et[n][m] = exp(Qt Kt^T), fused partial sum S[m] --------
// OPERAND-SWAPPED: A=Qt (rows=n), B=Kt (cols=m) -> m is the lane dim.
// 256^2 core (fine 2-phase), grid (16,16,4) x 512 thr, 64 KB = 2 blk/CU.
struct QKArgs {
  const unsigned short* Q[4]; const unsigned short* K[4]; unsigned short* T[4];
  float* pz;  // [4 z][16 nblk][4096 m] partial sums
};
__global__ __launch_bounds__(512) void k_qk(QKArgs a) {
  __shared__ unsigned short sh[32768];  // 64 KB
  int z = blockIdx.z;
  int nbase = blockIdx.y << 8;
  int mbase = blockIdx.x << 8;
  f32x4 acc[8][4];
#pragma unroll
  for (int i = 0; i < 8; ++i)
#pragma unroll
    for (int j = 0; j < 4; ++j) acc[i][j] = (f32x4){0.f, 0.f, 0.f, 0.f};
  gemm256(a.Q[z], a.K[z], nbase, mbase, acc, sh);

  const int tid = threadIdx.x, w = tid >> 6, lane = tid & 63;
  const int quad = lane >> 4, l16 = lane & 15;
  const int wm = (w >> 2) << 7, wn = (w & 3) << 6;
  unsigned short* T = a.T[z];
  float sjv[4] = {0.f, 0.f, 0.f, 0.f};
#pragma unroll
  for (int i = 0; i < 8; ++i) {
    int n0 = nbase + wm + ((i >> 2) << 6) + ((i & 3) << 4) + (quad << 2);
#pragma unroll
    for (int j = 0; j < 4; ++j) {
      int m = mbase + wn + (j << 4) + l16;
      float e0 = __expf(acc[i][j].x);
      float e1 = __expf(acc[i][j].y);
      float e2 = __expf(acc[i][j].z);
      float e3 = __expf(acc[i][j].w);
      T[(size_t)(n0 + 0) * 4096 + m] = f2bf(e0);
      T[(size_t)(n0 + 1) * 4096 + m] = f2bf(e1);
      T[(size_t)(n0 + 2) * 4096 + m] = f2bf(e2);
      T[(size_t)(n0 + 3) * 4096 + m] = f2bf(e3);
      sjv[j] += e0 + e1 + e2 + e3;
    }
  }
  __syncthreads();
  float* red = (float*)sh;  // [8 waves][64 m-local]
#pragma unroll
  for (int j = 0; j < 4; ++j) {
    float s = sjv[j];
    s += __shfl_xor(s, 16, 64);
    s += __shfl_xor(s, 32, 64);
    if (quad == 0) red[(w << 6) + (j << 4) + l16] = s;
  }
  __syncthreads();
  if (tid < 256) {
    float S = red[tid] + red[tid + 256];
    a.pz[((z << 4) + blockIdx.y) * 4096 + mbase + tid] = S;
  }
}

// ---------------- merge 16 partials -> c[m] = 1/S ------------------------
__global__ __launch_bounds__(256) void k_stats2(const float* __restrict__ pz,
                                                float* __restrict__ c) {
  int m = (blockIdx.x << 8) + threadIdx.x;
  int z = blockIdx.y;
  float S = 0.f;
#pragma unroll
  for (int k = 0; k < 16; ++k) S += pz[((z << 4) + k) * 4096 + m];
  c[z * 4096 + m] = 1.f / S;
}

// ---------------- V'[c][m] = V[c][m] * c[m] (in place) -------------------
struct VSArgs { unsigned short* V[4]; const float* c; };
__global__ __launch_bounds__(256) void k_vscale(VSArgs a) {
  int z = blockIdx.y;
  int t = blockIdx.x * 256 + threadIdx.x;
  int m0 = (t & 511) << 3;
  int row = t >> 9;
  unsigned short* p = a.V[z] + (size_t)row * 4096 + m0;
  const float* cz = a.c + z * 4096 + m0;
  int4 raw = *(const int4*)p;
  unsigned short* u = (unsigned short*)&raw;
#pragma unroll
  for (int j = 0; j < 8; ++j) u[j] = f2bf(bf2f(u[j]) * cz[j]);
  *(int4*)p = raw;
}

// ---------------- k_pv: P[kh] = V'[:, khalf] E[:, khalf]^T (split-K) -----
// (unchanged from r9 -- validated: 115 -> ~88 us)
struct PVArgs {
  const unsigned short* V[4];
  const unsigned short* P[4];  // Et[n][m]
  unsigned short* PP[2];       // partials per k-half
};
__global__ __launch_bounds__(512) void k_pv(PVArgs a) {
  __shared__ unsigned short sh[65536];  // 128 KB
  int x = blockIdx.x;            // x = kh + 2z + 8t -> XCD = x&7 = kh+2z
  int kh = x & 1;
  int z  = (x >> 1) & 3;
  int tt = x >> 3;               // 0..31
  int cb = tt & 1;
  int nb = tt >> 1;              // 0..15
  int cbase = cb << 8;
  int nbase = nb << 8;
  int khb = kh << 11;            // k-half base: 0 / 2048
  const unsigned short* Ag = a.V[z];   // V'[c][m], stride 4096
  const unsigned short* Bg = a.P[z];   // E[n][m],  stride 4096

  const int tid = threadIdx.x;
  const int w = tid >> 6, lane = tid & 63;
  const int quad = lane >> 4, l16 = lane & 15;
  const int wm = (w >> 2) << 7;   // c offset 0/128
  const int wn = (w & 3) << 6;    // n offset 0/64/128/192

  f32x4 acc[8][4];
#pragma unroll
  for (int i = 0; i < 8; ++i)
#pragma unroll
    for (int j = 0; j < 4; ++j) acc[i][j] = (f32x4){0.f, 0.f, 0.f, 0.f};

  auto stageA = [&](int kg, int ksub, unsigned short* buf) {
#pragma unroll
    for (int r = 0; r < 2; ++r) {
      int row = (tid >> 2) + (r << 7);
      int cg = (tid & 3) ^ ((row >> 1) & 3);
      async_copy16(Ag + (size_t)(cbase + row) * 4096 + kg + (ksub << 5) + (cg << 3),
                   buf + (ksub << 13) + (r << 12) + (w << 9));
    }
  };
  auto stageB = [&](int kg, int ksub, unsigned short* buf) {
#pragma unroll
    for (int r = 0; r < 2; ++r) {
      int row = (tid >> 2) + (r << 7);
      int cg = (tid & 3) ^ ((row >> 1) & 3);
      async_copy16(Bg + (size_t)(nbase + row) * 4096 + kg + (ksub << 5) + (cg << 3),
                   buf + 16384 + (ksub << 13) + (r << 12) + (w << 9));
    }
  };

  bf16x8 afv[4], bfv[4];
  auto rdA = [&](const unsigned short* buf, int ksub, int half) {
    const unsigned short* As = buf + (ksub << 13);
#pragma unroll
    for (int i = 0; i < 4; ++i) {
      int r = wm + (half << 6) + (i << 4) + l16;
      afv[i] = *(const bf16x8*)(As + (r << 5) + ((quad ^ ((r >> 1) & 3)) << 3));
    }
  };
  auto rdB = [&](const unsigned short* buf, int ksub) {
    const unsigned short* Bs = buf + 16384 + (ksub << 13);
#pragma unroll
    for (int j = 0; j < 4; ++j) {
      int r = wn + (j << 4) + l16;
      bfv[j] = *(const bf16x8*)(Bs + (r << 5) + ((quad ^ ((r >> 1) & 3)) << 3));
    }
  };
  auto mfmaQ = [&](int ib) {
#pragma unroll
    for (int i = 0; i < 4; ++i)
#pragma unroll
      for (int j = 0; j < 4; ++j)
        acc[ib + i][j] = __builtin_amdgcn_mfma_f32_16x16x32_bf16(afv[i], bfv[j], acc[ib + i][j], 0, 0, 0);
  };

  unsigned short* b0 = sh;
  unsigned short* b1 = sh + 32768;

  stageA(khb, 0, b0); stageA(khb, 1, b0); stageB(khb, 0, b0); stageB(khb, 1, b0);
  stageB(khb + 64, 0, b1); stageA(khb + 64, 0, b1); stageB(khb + 64, 1, b1);
  waitcnt_vm<6>();                 // tile0's 8 retired; tile1's 6 ride
  __builtin_amdgcn_s_barrier();

  for (int t = 0; t < 32; ++t) {
    unsigned short* cur = (t & 1) ? b1 : b0;
    unsigned short* nxt = (t & 1) ? b0 : b1;
    int kgc = khb + ((t + 2) << 6);
    rdB(cur, 0);
    rdA(cur, 0, 0);
    if (t + 1 < 32) stageA(khb + ((t + 1) << 6), 1, nxt);
    __builtin_amdgcn_s_barrier();
    __builtin_amdgcn_s_setprio(1); mfmaQ(0); __builtin_amdgcn_s_setprio(0);
    __builtin_amdgcn_s_barrier();
    rdA(cur, 0, 1);
    if (t + 2 < 32) stageB(kgc, 0, cur);
    __builtin_amdgcn_s_barrier();
    __builtin_amdgcn_s_setprio(1); mfmaQ(4); __builtin_amdgcn_s_setprio(0);
    __builtin_amdgcn_s_barrier();
    rdB(cur, 1);
    rdA(cur, 1, 0);
    if (t + 2 < 32) stageA(kgc, 0, cur);
    __builtin_amdgcn_s_barrier();
    __builtin_amdgcn_s_setprio(1); mfmaQ(0); __builtin_amdgcn_s_setprio(0);
    __builtin_amdgcn_s_barrier();
    rdA(cur, 1, 1);
    if (t + 2 < 32) stageB(kgc, 1, cur);
    __builtin_amdgcn_s_barrier();
    __builtin_amdgcn_s_setprio(1); mfmaQ(4); __builtin_amdgcn_s_setprio(0);
    if (t < 30) waitcnt_vm<6>(); else waitcnt_vm<0>();
    __builtin_amdgcn_s_barrier();
  }

  unsigned short* PP = a.PP[kh] + (size_t)z * 2097152;
#pragma unroll
  for (int i = 0; i < 8; ++i) {
    int c0 = cbase + wm + ((i >> 2) << 6) + ((i & 3) << 4) + (quad << 2);
#pragma unroll
    for (int j = 0; j < 4; ++j) {
      int n = nbase + wn + (j << 4) + l16;
      PP[(size_t)(c0 + 0) * 4096 + n] = f2bf(acc[i][j].x);
      PP[(size_t)(c0 + 1) * 4096 + n] = f2bf(acc[i][j].y);
      PP[(size_t)(c0 + 2) * 4096 + n] = f2bf(acc[i][j].z);
      PP[(size_t)(c0 + 3) * 4096 + n] = f2bf(acc[i][j].w);
    }
  }
}

// ---------------- k_red: out = relu(gamma*(P0+P1) + resid) ---------------
struct RArgs {
  const unsigned short* PP[2];
  const float* resid[4];
  const float* gamma[4];
  float* out[4];
};
__global__ __launch_bounds__(256) void k_red(RArgs a) {
  int z = blockIdx.y;
  size_t i = (((size_t)blockIdx.x << 8) + threadIdx.x) << 3;
  int4 q0 = *(const int4*)(a.PP[0] + (size_t)z * 2097152 + i);
  int4 q1 = *(const int4*)(a.PP[1] + (size_t)z * 2097152 + i);
  const unsigned short* u0 = (const unsigned short*)&q0;
  const unsigned short* u1 = (const unsigned short*)&q1;
  float g = a.gamma[z][0];
  const float* R = a.resid[z] + i;
  float4 r0 = *(const float4*)R;
  float4 r1 = *(const float4*)(R + 4);
  const float* rv = (const float*)&r0;
  const float* rw = (const float*)&r1;
  float res[8];
#pragma unroll
  for (int k = 0; k < 4; ++k)
    res[k] = fmaxf(g * (bf2f(u0[k]) + bf2f(u1[k])) + rv[k], 0.f);
#pragma unroll
  for (int k = 4; k < 8; ++k)
    res[k] = fmaxf(g * (bf2f(u0[k]) + bf2f(u1[k])) + rw[k - 4], 0.f);
  float* O = a.out[z] + i;
  *(float4*)O = *(float4*)res;
  *(float4*)(O + 4) = *(float4*)(res + 4);
}

// ---------------------------------------------------------------------------
extern "C" void kernel_launch(void* const* d_in, const int* in_sizes, int n_in,
                              void* d_out, int out_size, void* d_ws, size_t ws_size,
                              hipStream_t stream) {
  char* ws = (char*)d_ws;
  unsigned short* wb  = (unsigned short*)(ws);              //  6 x 512x512 bf16
  unsigned short* xt  = (unsigned short*)(ws + 3145728);    //  4 x [2][4096][512]
  unsigned short* qkv = (unsigned short*)(ws + 36700160);   // 12 x [4096x512]
  unsigned short* tt  = (unsigned short*)(ws + 87031808);   //  4 x [4096x4096]
  float* pz  = (float*)(ws + 3145728);                      // overlaps dead xt
  float* cb  = (float*)(ws + 3145728 + 2097152);
  // split-K partials reuse dead Q/K conv outputs (each exactly 16777216 B):
  unsigned short* pp0 = qkv;                          // slots 0-3 (Q_rd,K_rd)
  unsigned short* pp1 = qkv + (size_t)6 * 2097152;    // slots 6-9 (Q_dr,K_dr)

  // 1. weights -> bf16
  WArgs wa;
  for (int i = 0; i < 6; ++i) {
    wa.src[i] = (const float*)d_in[4 + 2 * i];
    wa.dst[i] = wb + (size_t)i * 262144;
  }
  k_cvtw<<<dim3(128, 6), 256, 0, stream>>>(wa);

  // 2. feature maps -> transposed bf16 Xt[b][n][c]
  TArgs ta;
  for (int ai = 0; ai < 4; ++ai) {
    ta.src[ai] = (const float*)d_in[ai];
    ta.dst[ai] = xt + (size_t)ai * 4194304;
  }
  k_tcvt<<<dim3(64, 16, 8), 256, 0, stream>>>(ta);

  // 3. six convs x two batches (256^2 core, 384 blocks x 512 thr)
  const int srcArr[6] = {2, 0, 3, 3, 1, 1};
  const int trans[6] = {1, 1, 0, 1, 1, 0};
  ConvArgs ca;
  for (int ci = 0; ci < 6; ++ci)
    for (int b = 0; b < 2; ++b) {
      int zz = ci * 2 + b;
      ca.W[zz] = wb + (size_t)ci * 262144;
      ca.X[zz] = xt + (size_t)srcArr[ci] * 4194304 + (size_t)b * 2097152;
      ca.bias[zz] = (const float*)d_in[5 + 2 * ci];
      ca.out[zz] = qkv + (size_t)zz * 2097152;
      ca.trans[zz] = trans[ci];
    }
  k_conv<<<dim3(16, 2, 12), 512, 0, stream>>>(ca);

  // 4. Et[n][m] = exp(Qt Kt^T) + fused partial sums (256^2 fine 2-phase)
  QKArgs qa;
  for (int path = 0; path < 2; ++path)
    for (int b = 0; b < 2; ++b) {
      int zz = path * 2 + b;
      qa.Q[zz] = qkv + (size_t)((path * 3 + 0) * 2 + b) * 2097152;  // Qt (rows=n)
      qa.K[zz] = qkv + (size_t)((path * 3 + 1) * 2 + b) * 2097152;  // Kt (cols=m)
      qa.T[zz] = tt + (size_t)zz * 16777216;
    }
  qa.pz = pz;
  k_qk<<<dim3(16, 16, 4), 512, 0, stream>>>(qa);

  // 5. merge partials -> c[m] = 1/S
  k_stats2<<<dim3(16, 4), 256, 0, stream>>>(pz, cb);

  // 6. V' = V * c[m]
  VSArgs va;
  for (int path = 0; path < 2; ++path)
    for (int b = 0; b < 2; ++b)
      va.V[path * 2 + b] = qkv + (size_t)((path * 3 + 2) * 2 + b) * 2097152;
  va.c = cb;
  k_vscale<<<dim3(1024, 4), 256, 0, stream>>>(va);

  // 7. split-K PV partials (256^2 tile, wave 128x64, 4-phase, full fill)
  PVArgs pa;
  for (int path = 0; path < 2; ++path)
    for (int b = 0; b < 2; ++b) {
      int zz = path * 2 + b;
      pa.V[zz] = qkv + (size_t)((path * 3 + 2) * 2 + b) * 2097152;
      pa.P[zz] = tt + (size_t)zz * 16777216;
    }
  pa.PP[0] = pp0;
  pa.PP[1] = pp1;
  k_pv<<<dim3(256), 512, 0, stream>>>(pa);

  // 8. reduce + fused epilogue
  RArgs ra;
  const float* resid_src[2] = {(const float*)d_in[2], (const float*)d_in[3]};
  const float* gsrc[2] = {(const float*)d_in[16], (const float*)d_in[17]};
  ra.PP[0] = pp0;
  ra.PP[1] = pp1;
  for (int path = 0; path < 2; ++path)
    for (int b = 0; b < 2; ++b) {
      int zz = path * 2 + b;
      ra.resid[zz] = resid_src[path] + (size_t)b * 2097152;
      ra.gamma[zz] = gsrc[path];
      ra.out[zz] = (float*)d_out + (size_t)zz * 2097152;
    }
  k_red<<<dim3(1024, 4), 256, 0, stream>>>(ra);
}

// Round 11
// 345.797 us; speedup vs baseline: 1.2095x; 1.0074x over previous
//
#include <hip/hip_runtime.h>
#include <stdint.h>

// ---------------------------------------------------------------------------
// FeatureMapTransformer: dual cross-attention (rd / dr paths), B=2, C=512,
// H=W=64 -> N=M=4096.
//   Qt[n][c], Kt[m][c] (transposed conv outs), V[c][m]        (bf16)
//   Et[n][m] = bf16(exp(sum_c Kt[m][c] Qt[n][c]))             (k_qk)
//   partial S[m] = sum_n exp(T) fused into k_qk               (k_qk)
//   c[m] = 1/S; V'[c][m] = V[c][m]*c[m]  (merged)             (k_scale)
//   O[c][n]  = sum_m V'[c][m] E[n][m]  (split-K bf16 GEMM)    (k_pv)
//   out = relu(gamma*(P0+P1) + resid)                         (k_red)
// r10: k_conv 256^2 core -12 us; k_qk FLAT at 98 (fine-phase null; r2's
// 5-blk also null) -> k_qk is not schedule- or occupancy-limited.
// Round-20: MFMA SHAPE. 32x32x16 pipe = 2495 TF vs 16x16x32's 2075
// (m06/m119, +20%) and halves MFMA instruction count at equal FLOP;
// operand bytes/FLOP unchanged (LDS load identical). k_qk only this
// round: gemm256q = r10 skeleton verbatim (same stages, barriers,
// vmcnt(2) stagger; B-frags for BOTH k-halves read in p0 so
// stageB(t+2)->cur keeps its region-safety proof), mfma replaced by
// v_mfma_f32_32x32x16_bf16 (acc f32x16[4][2], A-frag row=lane&31,
// k=(lane>>5)*8 -- CDNA pattern, symmetric to verified 16x16 frags).
// Epilogue remapped to verified 32x32 C/D layout: col=lane&31 (m),
// row=(reg&3)+8*(reg>>2)+4*(lane>>5) (n). Column sums: shfl_xor(32)
// then same red[]/pz path as r10 (layout-invariant).
// Also: k_stats2+k_vscale merged into k_scale (c in LDS per block,
// grid (16,4,8)): one launch + one pz pass saved.
// ---------------------------------------------------------------------------

typedef __attribute__((ext_vector_type(8))) __bf16 bf16x8;
typedef __attribute__((ext_vector_type(4))) float f32x4;
typedef __attribute__((ext_vector_type(16))) float f32x16;

__device__ __forceinline__ unsigned short f2bf(float f) {
  union { float f; unsigned u; } v; v.f = f;
  unsigned r = v.u + 0x7FFFu + ((v.u >> 16) & 1u);
  return (unsigned short)(r >> 16);
}
__device__ __forceinline__ float bf2f(unsigned short b) {
  union { unsigned u; float f; } v; v.u = ((unsigned)b) << 16;
  return v.f;
}

__device__ __forceinline__ void async_copy16(const unsigned short* g,
                                             unsigned short* l) {
  __builtin_amdgcn_global_load_lds(
      (const __attribute__((address_space(1))) unsigned int*)g,
      (__attribute__((address_space(3))) unsigned int*)l, 16, 0, 0);
}

// Counted VMEM wait (literal immediates only). Memory clobber pins all
// memory ops (ds_read / global_load_lds) on the correct side.
template <int N>
__device__ __forceinline__ void waitcnt_vm() {
  if constexpr (N == 0) asm volatile("s_waitcnt vmcnt(0)" ::: "memory");
  else if constexpr (N == 2) asm volatile("s_waitcnt vmcnt(2)" ::: "memory");
  else if constexpr (N == 4) asm volatile("s_waitcnt vmcnt(4)" ::: "memory");
  else if constexpr (N == 6) asm volatile("s_waitcnt vmcnt(6)" ::: "memory");
  else asm volatile("s_waitcnt vmcnt(8)" ::: "memory");
}

// ---------------- shared 256^2 GEMM core, 16x16x32 (k_conv) --------------
__device__ __forceinline__ void gemm256(
    const unsigned short* __restrict__ Ag, const unsigned short* __restrict__ Bg,
    int rowbase, int colbase, f32x4 (&acc)[8][4], unsigned short* sh) {
  const int tid = threadIdx.x;
  const int w = tid >> 6, lane = tid & 63;
  const int quad = lane >> 4, l16 = lane & 15;
  const int wm = (w >> 2) << 7;   // A-row offset 0/128
  const int wn = (w & 3) << 6;    // B-row offset 0/64/128/192
  const int srow = tid >> 2;                      // 0..127
  const int scg  = (tid & 3) ^ ((srow >> 1) & 3);

  auto stageA = [&](int kg, unsigned short* buf) {
#pragma unroll
    for (int r = 0; r < 2; ++r) {
      int row = srow + (r << 7);
      async_copy16(Ag + (size_t)(rowbase + row) * 512 + kg + (scg << 3),
                   buf + (r << 12) + (w << 9));
    }
  };
  auto stageB = [&](int kg, unsigned short* buf) {
#pragma unroll
    for (int r = 0; r < 2; ++r) {
      int row = srow + (r << 7);
      async_copy16(Bg + (size_t)(colbase + row) * 512 + kg + (scg << 3),
                   buf + 8192 + (r << 12) + (w << 9));
    }
  };
  bf16x8 af[4], bfv[4];
  auto rdA = [&](const unsigned short* buf, int half) {
#pragma unroll
    for (int i = 0; i < 4; ++i) {
      int r = wm + (half << 6) + (i << 4) + l16;
      af[i] = *(const bf16x8*)(buf + (r << 5) + ((quad ^ ((r >> 1) & 3)) << 3));
    }
  };
  auto rdB = [&](const unsigned short* buf) {
#pragma unroll
    for (int j = 0; j < 4; ++j) {
      int r = wn + (j << 4) + l16;
      bfv[j] = *(const bf16x8*)(buf + 8192 + (r << 5) + ((quad ^ ((r >> 1) & 3)) << 3));
    }
  };
  auto mfmaQ = [&](int ib) {
#pragma unroll
    for (int i = 0; i < 4; ++i)
#pragma unroll
      for (int j = 0; j < 4; ++j)
        acc[ib + i][j] = __builtin_amdgcn_mfma_f32_16x16x32_bf16(af[i], bfv[j], acc[ib + i][j], 0, 0, 0);
  };

  unsigned short* b0 = sh;
  unsigned short* b1 = sh + 16384;

  stageA(0, b0); stageB(0, b0); stageB(32, b1);
  waitcnt_vm<2>();
  __builtin_amdgcn_s_barrier();

  for (int t = 0; t < 16; ++t) {
    unsigned short* cur = (t & 1) ? b1 : b0;
    unsigned short* nxt = (t & 1) ? b0 : b1;
    rdB(cur);
    rdA(cur, 0);
    if (t + 1 < 16) stageA((t + 1) << 5, nxt);
    __builtin_amdgcn_s_barrier();
    __builtin_amdgcn_s_setprio(1); mfmaQ(0); __builtin_amdgcn_s_setprio(0);
    __builtin_amdgcn_s_barrier();
    rdA(cur, 1);
    if (t + 2 < 16) stageB((t + 2) << 5, cur);
    __builtin_amdgcn_s_barrier();
    __builtin_amdgcn_s_setprio(1); mfmaQ(4); __builtin_amdgcn_s_setprio(0);
    if (t < 14) waitcnt_vm<2>(); else waitcnt_vm<0>();
    __builtin_amdgcn_s_barrier();
  }
}

// ---------------- 256^2 GEMM core, 32x32x16 (k_qk) -----------------------
// Same stage/schedule skeleton as gemm256; fragments/mfma use the 32x32
// shape. acc[4 i][2 j] f32x16; A frag: row=lane&31, k=(lane>>5)*8 within
// the 16-k slice; B symmetric. Per tile: p0 reads B both k-halves + A
// k-half0 (8 reads), p1 reads A k-half1 (4 reads) -- B fully consumed in
// p0 so stageB(t+2)->cur at p1 keeps the r10 region-safety proof.
__device__ __forceinline__ void gemm256q(
    const unsigned short* __restrict__ Ag, const unsigned short* __restrict__ Bg,
    int rowbase, int colbase, f32x16 (&acc)[4][2], unsigned short* sh) {
  const int tid = threadIdx.x;
  const int w = tid >> 6, lane = tid & 63;
  const int l32 = lane & 31, lh = lane >> 5;
  const int wm = (w >> 2) << 7;   // A-row offset 0/128
  const int wn = (w & 3) << 6;    // B-row offset 0/64/128/192
  const int srow = tid >> 2;
  const int scg  = (tid & 3) ^ ((srow >> 1) & 3);

  auto stageA = [&](int kg, unsigned short* buf) {
#pragma unroll
    for (int r = 0; r < 2; ++r) {
      int row = srow + (r << 7);
      async_copy16(Ag + (size_t)(rowbase + row) * 512 + kg + (scg << 3),
                   buf + (r << 12) + (w << 9));
    }
  };
  auto stageB = [&](int kg, unsigned short* buf) {
#pragma unroll
    for (int r = 0; r < 2; ++r) {
      int row = srow + (r << 7);
      async_copy16(Bg + (size_t)(colbase + row) * 512 + kg + (scg << 3),
                   buf + 8192 + (r << 12) + (w << 9));
    }
  };
  bf16x8 af[4], bfv[2][2];
  // A frag i (rows wm+i*32..+31), k-half kh (0/1): chunk = kh*2 + lh
  auto rdA = [&](const unsigned short* buf, int kh) {
#pragma unroll
    for (int i = 0; i < 4; ++i) {
      int r = wm + (i << 5) + l32;
      int ck = (kh << 1) + lh;
      af[i] = *(const bf16x8*)(buf + (r << 5) + ((ck ^ ((r >> 1) & 3)) << 3));
    }
  };
  auto rdB4 = [&](const unsigned short* buf) {
#pragma unroll
    for (int j = 0; j < 2; ++j)
#pragma unroll
      for (int kh = 0; kh < 2; ++kh) {
        int r = wn + (j << 5) + l32;
        int ck = (kh << 1) + lh;
        bfv[j][kh] = *(const bf16x8*)(buf + 8192 + (r << 5) + ((ck ^ ((r >> 1) & 3)) << 3));
      }
  };
  auto mfmaK = [&](int kh) {
#pragma unroll
    for (int i = 0; i < 4; ++i)
#pragma unroll
      for (int j = 0; j < 2; ++j)
        acc[i][j] = __builtin_amdgcn_mfma_f32_32x32x16_bf16(af[i], bfv[j][kh], acc[i][j], 0, 0, 0);
  };

  unsigned short* b0 = sh;
  unsigned short* b1 = sh + 16384;

  stageA(0, b0); stageB(0, b0); stageB(32, b1);
  waitcnt_vm<2>();
  __builtin_amdgcn_s_barrier();

  for (int t = 0; t < 16; ++t) {
    unsigned short* cur = (t & 1) ? b1 : b0;
    unsigned short* nxt = (t & 1) ? b0 : b1;
    // p0: all B frags + A k-half0; stage A(t+1)->nxt
    rdB4(cur);
    rdA(cur, 0);
    if (t + 1 < 16) stageA((t + 1) << 5, nxt);
    __builtin_amdgcn_s_barrier();
    __builtin_amdgcn_s_setprio(1); mfmaK(0); __builtin_amdgcn_s_setprio(0);
    __builtin_amdgcn_s_barrier();
    // p1: A k-half1; stage B(t+2)->cur (cur.B fully read in p0)
    rdA(cur, 1);
    if (t + 2 < 16) stageB((t + 2) << 5, cur);
    __builtin_amdgcn_s_barrier();
    __builtin_amdgcn_s_setprio(1); mfmaK(1); __builtin_amdgcn_s_setprio(0);
    if (t < 14) waitcnt_vm<2>(); else waitcnt_vm<0>();
    __builtin_amdgcn_s_barrier();
  }
}

// ---------------- weight fp32 -> bf16 (vectorized) -----------------------
struct WArgs { const float* src[6]; unsigned short* dst[6]; };
__global__ __launch_bounds__(256) void k_cvtw(WArgs a) {
  int z = blockIdx.y;
  int i = (blockIdx.x * 256 + threadIdx.x) << 3;
  const float* s = a.src[z] + i;
  float4 v0 = *(const float4*)s;
  float4 v1 = *(const float4*)(s + 4);
  unsigned short pk[8] = {f2bf(v0.x), f2bf(v0.y), f2bf(v0.z), f2bf(v0.w),
                          f2bf(v1.x), f2bf(v1.y), f2bf(v1.z), f2bf(v1.w)};
  *(int4*)(a.dst[z] + i) = *(int4*)pk;
}

// ---------------- transpose+convert: x[b][c][n] f32 -> Xt[b][n][c] bf16 --
struct TArgs { const float* src[4]; unsigned short* dst[4]; };
__global__ __launch_bounds__(256) void k_tcvt(TArgs a) {
  __shared__ float tile[32][68];
  int z = blockIdx.z;  // array*2 + b
  const float* src = a.src[z >> 1] + (size_t)(z & 1) * (512 * 4096);
  unsigned short* dst = a.dst[z >> 1] + (size_t)(z & 1) * (4096 * 512);
  int n0 = blockIdx.x << 6;  // 64 n
  int c0 = blockIdx.y << 5;  // 32 c
  int tid = threadIdx.x;
  int q = tid & 15, r0 = tid >> 4;  // 16 lanes/row, 16 c-rows/pass
#pragma unroll
  for (int pass = 0; pass < 2; ++pass) {
    int r = r0 + (pass << 4);
    *(float4*)&tile[r][q << 2] =
        *(const float4*)(src + (size_t)(c0 + r) * 4096 + n0 + (q << 2));
  }
  __syncthreads();
  int j = tid >> 2, c8 = (tid & 3) << 3;  // n row j, 8 c's per thread
  unsigned short pk[8];
#pragma unroll
  for (int k = 0; k < 8; ++k) pk[k] = f2bf(tile[c8 + k][j]);
  *(int4*)(dst + (size_t)(n0 + j) * 512 + c0 + c8) = *(int4*)pk;
}

// ---------------- conv1x1 GEMMs: Y = W X^T + bias (256^2 core) -----------
struct ConvArgs {
  const unsigned short* W[12];
  const unsigned short* X[12];
  const float* bias[12];
  unsigned short* out[12];
  int trans[12];
};
__global__ __launch_bounds__(512) void k_conv(ConvArgs a) {
  __shared__ unsigned short sh[32768];  // 64 KB
  int z = blockIdx.z;
  int trans = a.trans[z];
  int rowbase = (trans ? blockIdx.x : blockIdx.y) << 8;
  int colbase = (trans ? blockIdx.y : blockIdx.x) << 8;
  const unsigned short* Ag = trans ? a.X[z] : a.W[z];
  const unsigned short* Bg = trans ? a.W[z] : a.X[z];
  f32x4 acc[8][4];
#pragma unroll
  for (int i = 0; i < 8; ++i)
#pragma unroll
    for (int j = 0; j < 4; ++j) acc[i][j] = (f32x4){0.f, 0.f, 0.f, 0.f};
  gemm256(Ag, Bg, rowbase, colbase, acc, sh);

  const int tid = threadIdx.x, w = tid >> 6, lane = tid & 63;
  const int quad = lane >> 4, l16 = lane & 15;
  const int wm = (w >> 2) << 7, wn = (w & 3) << 6;
  const float* bias = a.bias[z];
  unsigned short* out = a.out[z];
  if (trans) {
    float bo[4];
#pragma unroll
    for (int j = 0; j < 4; ++j) bo[j] = bias[colbase + wn + (j << 4) + l16];
#pragma unroll
    for (int i = 0; i < 8; ++i) {
      int n0 = rowbase + wm + ((i >> 2) << 6) + ((i & 3) << 4) + (quad << 2);
#pragma unroll
      for (int j = 0; j < 4; ++j) {
        int o = colbase + wn + (j << 4) + l16;
        out[(size_t)(n0 + 0) * 512 + o] = f2bf(acc[i][j].x + bo[j]);
        out[(size_t)(n0 + 1) * 512 + o] = f2bf(acc[i][j].y + bo[j]);
        out[(size_t)(n0 + 2) * 512 + o] = f2bf(acc[i][j].z + bo[j]);
        out[(size_t)(n0 + 3) * 512 + o] = f2bf(acc[i][j].w + bo[j]);
      }
    }
  } else {
#pragma unroll
    for (int i = 0; i < 8; ++i) {
      int o0 = rowbase + wm + ((i >> 2) << 6) + ((i & 3) << 4) + (quad << 2);
      float b0 = bias[o0], b1 = bias[o0 + 1], b2 = bias[o0 + 2], b3 = bias[o0 + 3];
#pragma unroll
      for (int j = 0; j < 4; ++j) {
        int n = colbase + wn + (j << 4) + l16;
        out[(size_t)(o0 + 0) * 4096 + n] = f2bf(acc[i][j].x + b0);
        out[(size_t)(o0 + 1) * 4096 + n] = f2bf(acc[i][j].y + b1);
        out[(size_t)(o0 + 2) * 4096 + n] = f2bf(acc[i][j].z + b2);
        out[(size_t)(o0 + 3) * 4096 + n] = f2bf(acc[i][j].w + b3);
      }
    }
  }
}

// ---------------- Et[n][m] = exp(Qt Kt^T), fused partial sum S[m] --------
// OPERAND-SWAPPED: A=Qt (rows=n), B=Kt (cols=m). 256^2 / 32x32x16 core.
// C/D mapping: m = mbase+wn+j*32+(lane&31); n = nbase+wm+i*32+(reg&3)+
// 8*(reg>>2)+4*(lane>>5).
struct QKArgs {
  const unsigned short* Q[4]; const unsigned short* K[4]; unsigned short* T[4];
  float* pz;  // [4 z][16 nblk][4096 m] partial sums
};
__global__ __launch_bounds__(512) void k_qk(QKArgs a) {
  __shared__ unsigned short sh[32768];  // 64 KB
  int z = blockIdx.z;
  int nbase = blockIdx.y << 8;
  int mbase = blockIdx.x << 8;
  f32x16 acc[4][2];
#pragma unroll
  for (int i = 0; i < 4; ++i)
#pragma unroll
    for (int j = 0; j < 2; ++j) acc[i][j] = (f32x16)(0.f);
  gemm256q(a.Q[z], a.K[z], nbase, mbase, acc, sh);

  const int tid = threadIdx.x, w = tid >> 6, lane = tid & 63;
  const int l32 = lane & 31, lh = lane >> 5;
  const int wm = (w >> 2) << 7, wn = (w & 3) << 6;
  unsigned short* T = a.T[z];
  float sjv2[2] = {0.f, 0.f};
#pragma unroll
  for (int i = 0; i < 4; ++i) {
    int nb0 = nbase + wm + (i << 5) + (lh << 2);
#pragma unroll
    for (int j = 0; j < 2; ++j) {
      int m = mbase + wn + (j << 5) + l32;
#pragma unroll
      for (int rq = 0; rq < 4; ++rq) {
#pragma unroll
        for (int rr = 0; rr < 4; ++rr) {
          float e = __expf(acc[i][j][(rq << 2) + rr]);
          T[(size_t)(nb0 + (rq << 3) + rr) * 4096 + m] = f2bf(e);
          sjv2[j] += e;
        }
      }
    }
  }
  __syncthreads();
  float* red = (float*)sh;  // [8 waves][64 m-local]
#pragma unroll
  for (int j = 0; j < 2; ++j) {
    float s = sjv2[j];
    s += __shfl_xor(s, 32, 64);
    if (lh == 0) red[(w << 6) + (j << 5) + l32] = s;
  }
  __syncthreads();
  if (tid < 256) {
    float S = red[tid] + red[tid + 256];
    a.pz[((z << 4) + blockIdx.y) * 4096 + mbase + tid] = S;
  }
}

// ---------------- k_scale: c[m]=1/sum(pz); V' = V * c[m] (merged) --------
// Grid (16 m-blocks, 4 z, 8 row-segs) x 256 thr. c[256] in LDS.
struct SCArgs { unsigned short* V[4]; const float* pz; };
__global__ __launch_bounds__(256) void k_scale(SCArgs a) {
  __shared__ float cs[256];
  int mbase = blockIdx.x << 8;
  int z = blockIdx.y;
  int rb = blockIdx.z << 6;
  int tid = threadIdx.x;
  float S = 0.f;
#pragma unroll
  for (int k = 0; k < 16; ++k) S += a.pz[((z << 4) + k) * 4096 + mbase + tid];
  cs[tid] = 1.f / S;
  __syncthreads();
  int mloc = (tid & 31) << 3;
  unsigned short* base = a.V[z] + mbase + mloc;
#pragma unroll
  for (int p = 0; p < 8; ++p) {
    int row = rb + (p << 3) + (tid >> 5);
    unsigned short* ptr = base + (size_t)row * 4096;
    int4 raw = *(const int4*)ptr;
    unsigned short* u = (unsigned short*)&raw;
#pragma unroll
    for (int q = 0; q < 8; ++q) u[q] = f2bf(bf2f(u[q]) * cs[mloc + q]);
    *(int4*)ptr = raw;
  }
}

// ---------------- k_pv: P[kh] = V'[:, khalf] E[:, khalf]^T (split-K) -----
// (unchanged from r9 -- validated)
struct PVArgs {
  const unsigned short* V[4];
  const unsigned short* P[4];  // Et[n][m]
  unsigned short* PP[2];       // partials per k-half
};
__global__ __launch_bounds__(512) void k_pv(PVArgs a) {
  __shared__ unsigned short sh[65536];  // 128 KB
  int x = blockIdx.x;            // x = kh + 2z + 8t -> XCD = x&7 = kh+2z
  int kh = x & 1;
  int z  = (x >> 1) & 3;
  int tt = x >> 3;               // 0..31
  int cb = tt & 1;
  int nb = tt >> 1;              // 0..15
  int cbase = cb << 8;
  int nbase = nb << 8;
  int khb = kh << 11;            // k-half base: 0 / 2048
  const unsigned short* Ag = a.V[z];   // V'[c][m], stride 4096
  const unsigned short* Bg = a.P[z];   // E[n][m],  stride 4096

  const int tid = threadIdx.x;
  const int w = tid >> 6, lane = tid & 63;
  const int quad = lane >> 4, l16 = lane & 15;
  const int wm = (w >> 2) << 7;   // c offset 0/128
  const int wn = (w & 3) << 6;    // n offset 0/64/128/192

  f32x4 acc[8][4];
#pragma unroll
  for (int i = 0; i < 8; ++i)
#pragma unroll
    for (int j = 0; j < 4; ++j) acc[i][j] = (f32x4){0.f, 0.f, 0.f, 0.f};

  auto stageA = [&](int kg, int ksub, unsigned short* buf) {
#pragma unroll
    for (int r = 0; r < 2; ++r) {
      int row = (tid >> 2) + (r << 7);
      int cg = (tid & 3) ^ ((row >> 1) & 3);
      async_copy16(Ag + (size_t)(cbase + row) * 4096 + kg + (ksub << 5) + (cg << 3),
                   buf + (ksub << 13) + (r << 12) + (w << 9));
    }
  };
  auto stageB = [&](int kg, int ksub, unsigned short* buf) {
#pragma unroll
    for (int r = 0; r < 2; ++r) {
      int row = (tid >> 2) + (r << 7);
      int cg = (tid & 3) ^ ((row >> 1) & 3);
      async_copy16(Bg + (size_t)(nbase + row) * 4096 + kg + (ksub << 5) + (cg << 3),
                   buf + 16384 + (ksub << 13) + (r << 12) + (w << 9));
    }
  };

  bf16x8 afv[4], bfv[4];
  auto rdA = [&](const unsigned short* buf, int ksub, int half) {
    const unsigned short* As = buf + (ksub << 13);
#pragma unroll
    for (int i = 0; i < 4; ++i) {
      int r = wm + (half << 6) + (i << 4) + l16;
      afv[i] = *(const bf16x8*)(As + (r << 5) + ((quad ^ ((r >> 1) & 3)) << 3));
    }
  };
  auto rdB = [&](const unsigned short* buf, int ksub) {
    const unsigned short* Bs = buf + 16384 + (ksub << 13);
#pragma unroll
    for (int j = 0; j < 4; ++j) {
      int r = wn + (j << 4) + l16;
      bfv[j] = *(const bf16x8*)(Bs + (r << 5) + ((quad ^ ((r >> 1) & 3)) << 3));
    }
  };
  auto mfmaQ = [&](int ib) {
#pragma unroll
    for (int i = 0; i < 4; ++i)
#pragma unroll
      for (int j = 0; j < 4; ++j)
        acc[ib + i][j] = __builtin_amdgcn_mfma_f32_16x16x32_bf16(afv[i], bfv[j], acc[ib + i][j], 0, 0, 0);
  };

  unsigned short* b0 = sh;
  unsigned short* b1 = sh + 32768;

  stageA(khb, 0, b0); stageA(khb, 1, b0); stageB(khb, 0, b0); stageB(khb, 1, b0);
  stageB(khb + 64, 0, b1); stageA(khb + 64, 0, b1); stageB(khb + 64, 1, b1);
  waitcnt_vm<6>();
  __builtin_amdgcn_s_barrier();

  for (int t = 0; t < 32; ++t) {
    unsigned short* cur = (t & 1) ? b1 : b0;
    unsigned short* nxt = (t & 1) ? b0 : b1;
    int kgc = khb + ((t + 2) << 6);
    rdB(cur, 0);
    rdA(cur, 0, 0);
    if (t + 1 < 32) stageA(khb + ((t + 1) << 6), 1, nxt);
    __builtin_amdgcn_s_barrier();
    __builtin_amdgcn_s_setprio(1); mfmaQ(0); __builtin_amdgcn_s_setprio(0);
    __builtin_amdgcn_s_barrier();
    rdA(cur, 0, 1);
    if (t + 2 < 32) stageB(kgc, 0, cur);
    __builtin_amdgcn_s_barrier();
    __builtin_amdgcn_s_setprio(1); mfmaQ(4); __builtin_amdgcn_s_setprio(0);
    __builtin_amdgcn_s_barrier();
    rdB(cur, 1);
    rdA(cur, 1, 0);
    if (t + 2 < 32) stageA(kgc, 0, cur);
    __builtin_amdgcn_s_barrier();
    __builtin_amdgcn_s_setprio(1); mfmaQ(0); __builtin_amdgcn_s_setprio(0);
    __builtin_amdgcn_s_barrier();
    rdA(cur, 1, 1);
    if (t + 2 < 32) stageB(kgc, 1, cur);
    __builtin_amdgcn_s_barrier();
    __builtin_amdgcn_s_setprio(1); mfmaQ(4); __builtin_amdgcn_s_setprio(0);
    if (t < 30) waitcnt_vm<6>(); else waitcnt_vm<0>();
    __builtin_amdgcn_s_barrier();
  }

  unsigned short* PP = a.PP[kh] + (size_t)z * 2097152;
#pragma unroll
  for (int i = 0; i < 8; ++i) {
    int c0 = cbase + wm + ((i >> 2) << 6) + ((i & 3) << 4) + (quad << 2);
#pragma unroll
    for (int j = 0; j < 4; ++j) {
      int n = nbase + wn + (j << 4) + l16;
      PP[(size_t)(c0 + 0) * 4096 + n] = f2bf(acc[i][j].x);
      PP[(size_t)(c0 + 1) * 4096 + n] = f2bf(acc[i][j].y);
      PP[(size_t)(c0 + 2) * 4096 + n] = f2bf(acc[i][j].z);
      PP[(size_t)(c0 + 3) * 4096 + n] = f2bf(acc[i][j].w);
    }
  }
}

// ---------------- k_red: out = relu(gamma*(P0+P1) + resid) ---------------
struct RArgs {
  const unsigned short* PP[2];
  const float* resid[4];
  const float* gamma[4];
  float* out[4];
};
__global__ __launch_bounds__(256) void k_red(RArgs a) {
  int z = blockIdx.y;
  size_t i = (((size_t)blockIdx.x << 8) + threadIdx.x) << 3;
  int4 q0 = *(const int4*)(a.PP[0] + (size_t)z * 2097152 + i);
  int4 q1 = *(const int4*)(a.PP[1] + (size_t)z * 2097152 + i);
  const unsigned short* u0 = (const unsigned short*)&q0;
  const unsigned short* u1 = (const unsigned short*)&q1;
  float g = a.gamma[z][0];
  const float* R = a.resid[z] + i;
  float4 r0 = *(const float4*)R;
  float4 r1 = *(const float4*)(R + 4);
  const float* rv = (const float*)&r0;
  const float* rw = (const float*)&r1;
  float res[8];
#pragma unroll
  for (int k = 0; k < 4; ++k)
    res[k] = fmaxf(g * (bf2f(u0[k]) + bf2f(u1[k])) + rv[k], 0.f);
#pragma unroll
  for (int k = 4; k < 8; ++k)
    res[k] = fmaxf(g * (bf2f(u0[k]) + bf2f(u1[k])) + rw[k - 4], 0.f);
  float* O = a.out[z] + i;
  *(float4*)O = *(float4*)res;
  *(float4*)(O + 4) = *(float4*)(res + 4);
}

// ---------------------------------------------------------------------------
extern "C" void kernel_launch(void* const* d_in, const int* in_sizes, int n_in,
                              void* d_out, int out_size, void* d_ws, size_t ws_size,
                              hipStream_t stream) {
  char* ws = (char*)d_ws;
  unsigned short* wb  = (unsigned short*)(ws);              //  6 x 512x512 bf16
  unsigned short* xt  = (unsigned short*)(ws + 3145728);    //  4 x [2][4096][512]
  unsigned short* qkv = (unsigned short*)(ws + 36700160);   // 12 x [4096x512]
  unsigned short* tt  = (unsigned short*)(ws + 87031808);   //  4 x [4096x4096]
  float* pz  = (float*)(ws + 3145728);                      // overlaps dead xt
  // split-K partials reuse dead Q/K conv outputs (each exactly 16777216 B):
  unsigned short* pp0 = qkv;                          // slots 0-3 (Q_rd,K_rd)
  unsigned short* pp1 = qkv + (size_t)6 * 2097152;    // slots 6-9 (Q_dr,K_dr)

  // 1. weights -> bf16
  WArgs wa;
  for (int i = 0; i < 6; ++i) {
    wa.src[i] = (const float*)d_in[4 + 2 * i];
    wa.dst[i] = wb + (size_t)i * 262144;
  }
  k_cvtw<<<dim3(128, 6), 256, 0, stream>>>(wa);

  // 2. feature maps -> transposed bf16 Xt[b][n][c]
  TArgs ta;
  for (int ai = 0; ai < 4; ++ai) {
    ta.src[ai] = (const float*)d_in[ai];
    ta.dst[ai] = xt + (size_t)ai * 4194304;
  }
  k_tcvt<<<dim3(64, 16, 8), 256, 0, stream>>>(ta);

  // 3. six convs x two batches (256^2 core, 384 blocks x 512 thr)
  const int srcArr[6] = {2, 0, 3, 3, 1, 1};
  const int trans[6] = {1, 1, 0, 1, 1, 0};
  ConvArgs ca;
  for (int ci = 0; ci < 6; ++ci)
    for (int b = 0; b < 2; ++b) {
      int zz = ci * 2 + b;
      ca.W[zz] = wb + (size_t)ci * 262144;
      ca.X[zz] = xt + (size_t)srcArr[ci] * 4194304 + (size_t)b * 2097152;
      ca.bias[zz] = (const float*)d_in[5 + 2 * ci];
      ca.out[zz] = qkv + (size_t)zz * 2097152;
      ca.trans[zz] = trans[ci];
    }
  k_conv<<<dim3(16, 2, 12), 512, 0, stream>>>(ca);

  // 4. Et[n][m] = exp(Qt Kt^T) + fused partial sums (256^2, 32x32 MFMA)
  QKArgs qa;
  for (int path = 0; path < 2; ++path)
    for (int b = 0; b < 2; ++b) {
      int zz = path * 2 + b;
      qa.Q[zz] = qkv + (size_t)((path * 3 + 0) * 2 + b) * 2097152;  // Qt (rows=n)
      qa.K[zz] = qkv + (size_t)((path * 3 + 1) * 2 + b) * 2097152;  // Kt (cols=m)
      qa.T[zz] = tt + (size_t)zz * 16777216;
    }
  qa.pz = pz;
  k_qk<<<dim3(16, 16, 4), 512, 0, stream>>>(qa);

  // 5+6. merged: c[m] = 1/sum(pz), V' = V * c[m]
  SCArgs sa;
  for (int path = 0; path < 2; ++path)
    for (int b = 0; b < 2; ++b)
      sa.V[path * 2 + b] = qkv + (size_t)((path * 3 + 2) * 2 + b) * 2097152;
  sa.pz = pz;
  k_scale<<<dim3(16, 4, 8), 256, 0, stream>>>(sa);

  // 7. split-K PV partials (256^2 tile, wave 128x64, 4-phase, full fill)
  PVArgs pa;
  for (int path = 0; path < 2; ++path)
    for (int b = 0; b < 2; ++b) {
      int zz = path * 2 + b;
      pa.V[zz] = qkv + (size_t)((path * 3 + 2) * 2 + b) * 2097152;
      pa.P[zz] = tt + (size_t)zz * 16777216;
    }
  pa.PP[0] = pp0;
  pa.PP[1] = pp1;
  k_pv<<<dim3(256), 512, 0, stream>>>(pa);

  // 8. reduce + fused epilogue
  RArgs ra;
  const float* resid_src[2] = {(const float*)d_in[2], (const float*)d_in[3]};
  const float* gsrc[2] = {(const float*)d_in[16], (const float*)d_in[17]};
  ra.PP[0] = pp0;
  ra.PP[1] = pp1;
  for (int path = 0; path < 2; ++path)
    for (int b = 0; b < 2; ++b) {
      int zz = path * 2 + b;
      ra.resid[zz] = resid_src[path] + (size_t)b * 2097152;
      ra.gamma[zz] = gsrc[path];
      ra.out[zz] = (float*)d_out + (size_t)zz * 2097152;
    }
  k_red<<<dim3(1024, 4), 256, 0, stream>>>(ra);
}